// Round 15
// baseline (283.700 us; speedup 1.0000x reference)
//
#include <hip/hip_runtime.h>

typedef _Float16 f16x8 __attribute__((ext_vector_type(8)));
typedef _Float16 f16x4 __attribute__((ext_vector_type(4)));
typedef __fp16 h16x2 __attribute__((ext_vector_type(2)));
typedef float f32x4 __attribute__((ext_vector_type(4)));
typedef float f32x16 __attribute__((ext_vector_type(16)));

#define BN_EPS 1e-5f
#define SQRT32 5.656854249492381f
#define LOG2E  1.4426950408889634f

typedef const __attribute__((address_space(1))) void* gas_p;
typedef __attribute__((address_space(3))) void* las_p;

// ---------------------------------------------------------------- prep (merged)
// z<16: x [b][c=384][n] fp32 -> xT_hi/lo [b][n][c] fp16 planes (transpose+split).
// z==16: weight conversion + BN affine fold. (wqk lo plane no longer needed.)
__global__ __launch_bounds__(256) void prep(
    const float* __restrict__ x,
    const float* __restrict__ wq, const float* __restrict__ wk,
    const float* __restrict__ wv, const float* __restrict__ wp,
    const float* __restrict__ bnq, const float* __restrict__ bnk,
    const float* __restrict__ bnv, const float* __restrict__ bnp,
    _Float16* __restrict__ xT_hi, _Float16* __restrict__ xT_lo,
    _Float16* __restrict__ wqk_h,
    _Float16* __restrict__ wv_h,  _Float16* __restrict__ wp_h,
    float* __restrict__ s_qkv, float* __restrict__ t_qkv,
    float* __restrict__ s_p,   float* __restrict__ t_p)
{
    __shared__ float Tx[64][65];
    const int t = threadIdx.x;
    if (blockIdx.z < 16) {
        const int ct = blockIdx.x, nt = blockIdx.y, b = blockIdx.z;
        const int c0 = ct * 64, n0 = nt * 64;
        {
            int tr = t >> 4, tc = (t & 15) * 4;
            #pragma unroll
            for (int p = 0; p < 4; p++) {
                int r = tr + p * 16;
                float4 v = *(const float4*)(x + ((size_t)(b * 384 + c0 + r)) * 1024 + n0 + tc);
                Tx[r][tc + 0] = v.x; Tx[r][tc + 1] = v.y; Tx[r][tc + 2] = v.z; Tx[r][tc + 3] = v.w;
            }
        }
        __syncthreads();
        {
            int nn = t >> 2, cc = (t & 3) * 16;
            f16x8 h0, h1, l0, l1;
            #pragma unroll
            for (int i = 0; i < 8; i++) {
                float v = Tx[cc + i][nn];
                _Float16 hh = (_Float16)v;
                h0[i] = hh; l0[i] = (_Float16)(v - (float)hh);
            }
            #pragma unroll
            for (int i = 0; i < 8; i++) {
                float v = Tx[cc + 8 + i][nn];
                _Float16 hh = (_Float16)v;
                h1[i] = hh; l1[i] = (_Float16)(v - (float)hh);
            }
            size_t o = ((size_t)(b * 1024 + n0 + nn)) * 384 + c0 + cc;
            *(f16x8*)(xT_hi + o) = h0; *(f16x8*)(xT_hi + o + 8) = h1;
            *(f16x8*)(xT_lo + o) = l0; *(f16x8*)(xT_lo + o + 8) = l1;
        }
    } else {
        const int NQK = 512 * 384, NV = 1024 * 384, NP = 384 * 1024;
        int tid = (blockIdx.y * 6 + blockIdx.x) * 256 + t;       // 0..24575
        for (int i = tid; i < NQK + NV + NP; i += 24576) {
            if (i < NQK) {
                int o = i / 384, c = i - o * 384;
                float v = (o < 256) ? wq[o * 384 + c] : wk[(o - 256) * 384 + c];
                wqk_h[i] = (_Float16)v;
            } else if (i < NQK + NV) {
                wv_h[i - NQK] = (_Float16)wv[i - NQK];
            } else {
                wp_h[i - NQK - NV] = (_Float16)wp[i - NQK - NV];
            }
        }
        if (tid < 1536) {
            int i = tid;
            float g, be, m, v;
            if (i < 256)      { int o = i;       g = bnq[o]; be = bnq[256 + o];  m = bnq[512 + o];  v = bnq[768 + o]; }
            else if (i < 512) { int o = i - 256; g = bnk[o]; be = bnk[256 + o];  m = bnk[512 + o];  v = bnk[768 + o]; }
            else              { int o = i - 512; g = bnv[o]; be = bnv[1024 + o]; m = bnv[2048 + o]; v = bnv[3072 + o]; }
            float s = g * rsqrtf(v + BN_EPS);
            float tt = be - m * s;
            // fold /scale (= *sqrt(kd)) AND log2(e) (exp2 softmax) into Q's affine
            if (i < 256) { s *= SQRT32 * LOG2E; tt *= SQRT32 * LOG2E; }
            s_qkv[i] = s; t_qkv[i] = tt;
        } else if (tid < 1536 + 384) {
            int o = tid - 1536;
            float g = bnp[o], be = bnp[384 + o], m = bnp[768 + o], v = bnp[1152 + o];
            float s = g * rsqrtf(v + BN_EPS);
            s_p[o] = s; t_p[o] = be - m * s;
        }
    }
}

// ---------------------------------------------------------------- gemm_qkv
// m97-style staging; vectorized epilogues.
// bx<4 (Q/K): 2-term (w_h*x_h + w_h*x_lo; w-lo term dropped -- w ~0.05*N(0,1)
// quantization is the smallest score-error source; budget measured OK).
// Q and K both stored hi-plane only (K-lo dropped this round).
// bx>=4 (V): 1-term f16 -> PV-permuted vbuf.
__global__ __launch_bounds__(256, 2) void gemm_qkv(
    const _Float16* __restrict__ wqk_h,
    const _Float16* __restrict__ wv_h,
    const _Float16* __restrict__ xT_hi, const _Float16* __restrict__ xT_lo,
    const float* __restrict__ S, const float* __restrict__ T,
    _Float16* __restrict__ qT_h, _Float16* __restrict__ kT_h,
    _Float16* __restrict__ vbuf)
{
    __shared__ __align__(16) _Float16 As_h[128 * 64];   // 16 KB each
    __shared__ __align__(16) _Float16 Bs_h[128 * 64];
    __shared__ __align__(16) _Float16 Bs_l[128 * 64];
    const int t = threadIdx.x, lane = t & 63, w = t >> 6;
    const int wr = w >> 1, wc = w & 1, l16 = lane & 15, lq = lane >> 4;
    const int bx = blockIdx.x, n0 = blockIdx.y * 128, b = blockIdx.z;
    const bool isv = bx >= 4;
    const int o0 = isv ? (bx - 4) * 128 : bx * 128;
    const _Float16* __restrict__ Ah = isv ? wv_h : wqk_h;

    f32x4 acc[4][4] = {};

    for (int kb = 0; kb < 384; kb += 64) {
        __syncthreads();
        // stage via global_load_lds: LDS[row][s] = global[row][s^(row&7)]
        #pragma unroll
        for (int p = 0; p < 4; p++) {
            int g = t + p * 256, row = g >> 3, s = g & 7;
            int col = ((s ^ (row & 7)) * 8);
            __builtin_amdgcn_global_load_lds(
                (gas_p)(const void*)(Ah + (size_t)(o0 + row) * 384 + kb + col),
                (las_p)(void*)&As_h[(p * 256 + w * 64) * 8], 16, 0, 0);
        }
        #pragma unroll
        for (int p = 0; p < 4; p++) {
            int g = t + p * 256, row = g >> 3, s = g & 7;
            int col = ((s ^ (row & 7)) * 8);
            __builtin_amdgcn_global_load_lds(
                (gas_p)(const void*)(xT_hi + ((size_t)(b * 1024) + n0 + row) * 384 + kb + col),
                (las_p)(void*)&Bs_h[(p * 256 + w * 64) * 8], 16, 0, 0);
        }
        if (!isv) {
            #pragma unroll
            for (int p = 0; p < 4; p++) {
                int g = t + p * 256, row = g >> 3, s = g & 7;
                int col = ((s ^ (row & 7)) * 8);
                __builtin_amdgcn_global_load_lds(
                    (gas_p)(const void*)(xT_lo + ((size_t)(b * 1024) + n0 + row) * 384 + kb + col),
                    (las_p)(void*)&Bs_l[(p * 256 + w * 64) * 8], 16, 0, 0);
            }
        }
        __syncthreads();   // drains DMA (vmcnt 0) + joins waves

        if (!isv) {
            // A = w tiles (o rows), B = x tiles (n cols) -> D[o][n]
            #pragma unroll
            for (int kk = 0; kk < 2; kk++) {
                const int sl = ((kk * 4 + lq) ^ (l16 & 7)) * 8;
                f16x8 awh[4], bxh[4], bxl[4];
                #pragma unroll
                for (int i = 0; i < 4; i++)
                    awh[i] = *(const f16x8*)(&As_h[(wr * 64 + i * 16 + l16) * 64 + sl]);
                #pragma unroll
                for (int j = 0; j < 4; j++) {
                    int row = wc * 64 + j * 16 + l16;
                    bxh[j] = *(const f16x8*)(&Bs_h[row * 64 + sl]);
                    bxl[j] = *(const f16x8*)(&Bs_l[row * 64 + sl]);
                }
                #pragma unroll
                for (int i = 0; i < 4; i++)
                    #pragma unroll
                    for (int j = 0; j < 4; j++) {
                        acc[i][j] = __builtin_amdgcn_mfma_f32_16x16x32_f16(awh[i], bxh[j], acc[i][j], 0, 0, 0);
                        acc[i][j] = __builtin_amdgcn_mfma_f32_16x16x32_f16(awh[i], bxl[j], acc[i][j], 0, 0, 0);
                    }
            }
        } else {
            // A = x tiles (n rows), B = wv tiles (o cols) -> D[n][o]
            #pragma unroll
            for (int kk = 0; kk < 2; kk++) {
                const int sl = ((kk * 4 + lq) ^ (l16 & 7)) * 8;
                f16x8 axh[4], bwv[4];
                #pragma unroll
                for (int i = 0; i < 4; i++)
                    axh[i] = *(const f16x8*)(&Bs_h[(wr * 64 + i * 16 + l16) * 64 + sl]);
                #pragma unroll
                for (int j = 0; j < 4; j++)
                    bwv[j] = *(const f16x8*)(&As_h[(wc * 64 + j * 16 + l16) * 64 + sl]);
                #pragma unroll
                for (int i = 0; i < 4; i++)
                    #pragma unroll
                    for (int j = 0; j < 4; j++)
                        acc[i][j] = __builtin_amdgcn_mfma_f32_16x16x32_f16(axh[i], bwv[j], acc[i][j], 0, 0, 0);
            }
        }
    }

    if (!isv) {
        // D[o][n]: lane holds o = o0+wr*64+i*16+lq*4+r (4 consecutive), n fixed.
        #pragma unroll
        for (int i = 0; i < 4; i++) {
            int ob = o0 + wr * 64 + i * 16 + lq * 4;
            float4 sc4 = *(const float4*)(S + ob);
            float4 sh4 = *(const float4*)(T + ob);
            #pragma unroll
            for (int j = 0; j < 4; j++) {
                int n = n0 + wc * 64 + j * 16 + l16;
                f16x4 hv;
                #pragma unroll
                for (int r = 0; r < 4; r++)
                    hv[r] = (_Float16)(acc[i][j][r] * ((const float*)&sc4)[r] + ((const float*)&sh4)[r]);
                if (ob < 256) {
                    size_t idx = (((size_t)(b * 8) + (ob >> 5)) * 1024 + n) * 32 + (ob & 31);
                    *(f16x4*)(qT_h + idx) = hv;
                } else {
                    int oo = ob - 256;
                    int hd = oo >> 5, c = oo & 31;
                    int f = ((n >> 5) & 1) * 2 + (c >> 4);           // (sub, kh)
                    size_t idx = ((((size_t)(b * 8 + hd) * 16 + (n >> 6)) * 4 + f) * 64
                                  + ((c >> 3) & 1) * 32 + (n & 31)) * 8 + (c & 7);
                    *(f16x4*)(kT_h + idx) = hv;
                }
            }
        }
    } else {
        // D[n][o]: lane holds n (4 consecutive). PV-fragment permutation:
        // k=i*16+lq*4+r -> ep=i*16+(lq&1)*8+(lq>>1)*4+r (consecutive in r).
        #pragma unroll
        for (int i = 0; i < 4; i++) {
            int epb = i * 16 + (lq & 1) * 8 + (lq >> 1) * 4;
            int nhi = n0 + wr * 64;                       // n & ~63
            #pragma unroll
            for (int j = 0; j < 4; j++) {
                int o = o0 + wc * 64 + j * 16 + l16;
                float sc = S[512 + o], sh = T[512 + o];
                f16x4 vv;
                #pragma unroll
                for (int r = 0; r < 4; r++)
                    vv[r] = (_Float16)(acc[i][j][r] * sc + sh);
                *(f16x4*)(vbuf + ((size_t)(b * 1024) + o) * 1024 + nhi + epb) = vv;
            }
        }
    }
}

// ---------------------------------------------------------------- attn
// Round-14 verified structure; ONLY change: K consumed hi-plane only
// (symmetric to the verified Q-lo drop, measured +1.3 error in quadrature).
// QK = 1 MFMA per K-sub per q-half -> 4 per iter (was 8). K DMA + ds_reads
// halve; LDS 64 -> 56 KB; QK dep chain 2-deep.
__global__ __launch_bounds__(256, 2) void attn(
    const _Float16* __restrict__ qT_h,
    const _Float16* __restrict__ kT_h,
    const _Float16* __restrict__ vbuf,
    _Float16* __restrict__ xxT_h, _Float16* __restrict__ xxT_l)
{
    __shared__ __align__(16) _Float16 Vs[3][128 * 64];   // 48 KB (triple)
    __shared__ __align__(16) _Float16 Ksh[2][2048];      // 8 KB
    const int t = threadIdx.x, lane = t & 63, w = t >> 6;
    const int L = lane & 31, hl = lane >> 5;
    const int bh = blockIdx.x, qt = blockIdx.y;
    const int b = bh >> 3, h = bh & 7;
    const size_t vbase = ((size_t)(b * 1024) + h * 128) * 1024;

    // Q B-frags (hi plane only); once per block
    f16x8 bq_h[2];
    {
        int q = qt * 128 + w * 32 + L;
        #pragma unroll
        for (int kh = 0; kh < 2; kh++) {
            size_t base = ((size_t)(bh * 1024) + q) * 32 + kh * 16 + hl * 8;
            bq_h[kh] = *(const f16x8*)(qT_h + base);
        }
    }

    f32x16 o_acc[4] = {};
    float m_st = -INFINITY, l_st = 0.f;
    f16x8 pf[4];        // P(kt-1), consumed one iteration later

    #define DMA_TILE(vb, kb, kt_)                                                  \
        {                                                                          \
            size_t ktb = (size_t)(bh * 16 + (kt_)) * 2048 + (size_t)t * 8;         \
            __builtin_amdgcn_global_load_lds((gas_p)(const void*)(kT_h + ktb),     \
                                             (las_p)(void*)&Ksh[kb][w * 512], 16, 0, 0); \
            _Pragma("unroll")                                                      \
            for (int p = 0; p < 4; p++) {                                          \
                int g2 = t + p * 256;                                              \
                int d = g2 >> 3;                                                   \
                int kcg = (g2 & 7) ^ (d & 7);                                      \
                const _Float16* src = vbuf + vbase + (size_t)d * 1024              \
                                      + (kt_) * 64 + kcg * 8;                      \
                _Float16* dst = &Vs[vb][(p * 256 + w * 64) * 8];                   \
                __builtin_amdgcn_global_load_lds((gas_p)(const void*)src,          \
                                                 (las_p)(void*)dst, 16, 0, 0);     \
            }                                                                      \
        }

    DMA_TILE(0, 0, 0)
    __syncthreads();

    for (int kt = 0; kt < 16; kt++) {
        const int kcur = kt & 1;
        const int vprv = (kt + 2) % 3;       // buffer holding tile kt-1

        if (kt < 15) DMA_TILE((kt + 1) % 3, kcur ^ 1, kt + 1)

        // K frags from LDS (lgkmcnt only -- DMA stays in flight)
        const _Float16* khp = &Ksh[kcur][lane * 8];
        f16x8 K0h = *(const f16x8*)(khp);
        f16x8 K1h = *(const f16x8*)(khp + 512);
        f16x8 K2h = *(const f16x8*)(khp + 1024);
        f16x8 K3h = *(const f16x8*)(khp + 1536);

        __builtin_amdgcn_s_setprio(1);
        f32x16 c0 = {}, c1 = {};
        c0 = __builtin_amdgcn_mfma_f32_32x32x16_f16(K0h, bq_h[0], c0, 0, 0, 0);
        c1 = __builtin_amdgcn_mfma_f32_32x32x16_f16(K2h, bq_h[0], c1, 0, 0, 0);
        c0 = __builtin_amdgcn_mfma_f32_32x32x16_f16(K1h, bq_h[1], c0, 0, 0, 0);
        c1 = __builtin_amdgcn_mfma_f32_32x32x16_f16(K3h, bq_h[1], c1, 0, 0, 0);
        __builtin_amdgcn_s_setprio(0);

        // ---- PV(kt-1): independent of c0/c1, fills QK's latency shadow ----
        if (kt) {
            __builtin_amdgcn_s_setprio(1);
            #pragma unroll
            for (int s = 0; s < 4; s++) {
                int cp = (2 * s + hl) ^ (L & 7);
                #pragma unroll
                for (int dt = 0; dt < 4; dt++) {
                    f16x8 avp = *(const f16x8*)(&Vs[vprv][(dt * 32 + L) * 64 + cp * 8]);
                    o_acc[dt] = __builtin_amdgcn_mfma_f32_32x32x16_f16(avp, pf[s], o_acc[dt], 0, 0, 0);
                }
            }
            __builtin_amdgcn_s_setprio(0);
        }

        // ---- softmax(kt): overlaps PV's MFMA execution ----
        // row-max via max3 fusion (fmaxf(fmaxf(a,b),c) -> v_max3_f32)
        #define EL(e) ((e) < 16 ? c0[e] : c1[(e) - 16])
        float t1[11];
        #pragma unroll
        for (int g = 0; g < 10; g++)
            t1[g] = fmaxf(fmaxf(EL(3 * g), EL(3 * g + 1)), EL(3 * g + 2));
        t1[10] = fmaxf(EL(30), EL(31));
        #undef EL
        float t2a = fmaxf(fmaxf(t1[0], t1[1]), t1[2]);
        float t2b = fmaxf(fmaxf(t1[3], t1[4]), t1[5]);
        float t2c = fmaxf(fmaxf(t1[6], t1[7]), t1[8]);
        float t2d = fmaxf(t1[9], t1[10]);
        float mx0 = fmaxf(fmaxf(t2a, t2b), fmaxf(t2c, t2d));
        float mx = fmaxf(mx0, __shfl_xor(mx0, 32, 64));

        // defer-max: only rescale when the row max grows by > 8 (p <= 2^8 in f16)
        if (__any(mx > m_st + 8.f)) {
            float mnew = fmaxf(m_st, mx);
            float a = exp2f(m_st - mnew);
            l_st *= a;
            #pragma unroll
            for (int dt = 0; dt < 4; dt++)
                #pragma unroll
                for (int i = 0; i < 16; i++) o_acc[dt][i] *= a;
            m_st = mnew;
        }

        // exp -> packed f16 (cvt_pkrtz), partial-sum trees; store into pf for
        // consumption NEXT iteration
        float rs = 0.f;
        #pragma unroll
        for (int s = 0; s < 4; s++) {
            float pv[8];
            #pragma unroll
            for (int j = 0; j < 8; j++) {
                float cv = (s < 2) ? c0[(s & 1) * 8 + j] : c1[(s & 1) * 8 + j];
                pv[j] = exp2f(cv - m_st);
            }
            rs += ((pv[0] + pv[1]) + (pv[2] + pv[3])) + ((pv[4] + pv[5]) + (pv[6] + pv[7]));
            union { f16x8 v; h16x2 hh[4]; } u;
            #pragma unroll
            for (int j = 0; j < 4; j++)
                u.hh[j] = __builtin_amdgcn_cvt_pkrtz(pv[2 * j], pv[2 * j + 1]);
            pf[s] = u.v;
        }
        l_st += rs;

        if (kt < 15) __syncthreads();   // drains this iter's DMA + joins waves
    }
    #undef DMA_TILE

    // epilogue PV(15): tile 15 lives in Vs[15 % 3 == 0]
    {
        __builtin_amdgcn_s_setprio(1);
        #pragma unroll
        for (int s = 0; s < 4; s++) {
            int cp = (2 * s + hl) ^ (L & 7);
            #pragma unroll
            for (int dt = 0; dt < 4; dt++) {
                f16x8 avp = *(const f16x8*)(&Vs[0][(dt * 32 + L) * 64 + cp * 8]);
                o_acc[dt] = __builtin_amdgcn_mfma_f32_32x32x16_f16(avp, pf[s], o_acc[dt], 0, 0, 0);
            }
        }
        __builtin_amdgcn_s_setprio(0);
    }

    l_st += __shfl_xor(l_st, 32, 64);

    // epilogue: normalize, split hi/lo, store xxT[b][n=q][d]
    {
        float rl = 1.f / l_st;
        int q = qt * 128 + w * 32 + L;
        #pragma unroll
        for (int dt = 0; dt < 4; dt++) {
            #pragma unroll
            for (int gg = 0; gg < 4; gg++) {
                f16x4 hv, lv;
                #pragma unroll
                for (int rr = 0; rr < 4; rr++) {
                    float v = o_acc[dt][gg * 4 + rr] * rl;
                    _Float16 hh = (_Float16)v;
                    hv[rr] = hh; lv[rr] = (_Float16)(v - (float)hh);
                }
                size_t o = ((size_t)(b * 1024) + q) * 1024 + h * 128 + dt * 32 + gg * 8 + hl * 4;
                *(f16x4*)(xxT_h + o) = hv;
                *(f16x4*)(xxT_l + o) = lv;
            }
        }
    }
}

// ---------------------------------------------------------------- gemm_out
// (unchanged from round 12/14 -- verified pass) 1-term f16 on xx_hi.
__global__ __launch_bounds__(256, 2) void gemm_out(
    const _Float16* __restrict__ wp_h,
    const _Float16* __restrict__ xxT_h,
    const float* __restrict__ S, const float* __restrict__ T,
    float* __restrict__ out)
{
    __shared__ __align__(16) _Float16 As[128 * 64];   // 16 KB (wp, rows o)
    __shared__ __align__(16) _Float16 Bh[64 * 64];    // 8 KB (xx hi, rows n)
    const int t = threadIdx.x, lane = t & 63, w = t >> 6;
    const int wr = w >> 1, wc = w & 1, l16 = lane & 15, lq = lane >> 4;
    const int o0 = blockIdx.x * 128, n0 = blockIdx.y * 64, b = blockIdx.z;

    f32x4 acc[2][4] = {};   // [i: n-subtile][j: o-subtile]

    for (int kb = 0; kb < 1024; kb += 64) {
        __syncthreads();
        #pragma unroll
        for (int p = 0; p < 4; p++) {
            int g = t + p * 256, row = g >> 3, s = g & 7;
            int col = ((s ^ (row & 7)) * 8);
            __builtin_amdgcn_global_load_lds(
                (gas_p)(const void*)(wp_h + (size_t)(o0 + row) * 1024 + kb + col),
                (las_p)(void*)&As[(p * 256 + w * 64) * 8], 16, 0, 0);
        }
        #pragma unroll
        for (int p = 0; p < 2; p++) {
            int g = t + p * 256, row = g >> 3, s = g & 7;
            int col = ((s ^ (row & 7)) * 8);
            size_t src = ((size_t)(b * 1024) + n0 + row) * 1024 + kb + col;
            __builtin_amdgcn_global_load_lds(
                (gas_p)(const void*)(xxT_h + src),
                (las_p)(void*)&Bh[(p * 256 + w * 64) * 8], 16, 0, 0);
        }
        __syncthreads();

        #pragma unroll
        for (int kk = 0; kk < 2; kk++) {
            const int sl = ((kk * 4 + lq) ^ (l16 & 7)) * 8;
            f16x8 axh[2], bw[4];
            #pragma unroll
            for (int i = 0; i < 2; i++)
                axh[i] = *(const f16x8*)(&Bh[(wc * 32 + i * 16 + l16) * 64 + sl]);
            #pragma unroll
            for (int j = 0; j < 4; j++)
                bw[j] = *(const f16x8*)(&As[(wr * 64 + j * 16 + l16) * 64 + sl]);
            #pragma unroll
            for (int i = 0; i < 2; i++)
                #pragma unroll
                for (int j = 0; j < 4; j++)
                    acc[i][j] = __builtin_amdgcn_mfma_f32_16x16x32_f16(axh[i], bw[j], acc[i][j], 0, 0, 0);
        }
    }

    // D[n][o]: n = n0+wc*32+i*16+lq*4+r (consecutive), o = o0+wr*64+j*16+l16.
    #pragma unroll
    for (int i = 0; i < 2; i++) {
        int nb = n0 + wc * 32 + i * 16 + lq * 4;
        #pragma unroll
        for (int j = 0; j < 4; j++) {
            int o = o0 + wr * 64 + j * 16 + l16;
            float sc = S[o], sh = T[o];
            float4 vv;
            vv.x = acc[i][j][0] * sc + sh;
            vv.y = acc[i][j][1] * sc + sh;
            vv.z = acc[i][j][2] * sc + sh;
            vv.w = acc[i][j][3] * sc + sh;
            *(float4*)(out + ((size_t)(b * 384) + o) * 1024 + nb) = vv;
        }
    }
}

// ---------------------------------------------------------------- launch

extern "C" void kernel_launch(void* const* d_in, const int* in_sizes, int n_in,
                              void* d_out, int out_size, void* d_ws, size_t ws_size,
                              hipStream_t stream) {
    const float* x   = (const float*)d_in[0];
    const float* wq  = (const float*)d_in[1];
    const float* bnq = (const float*)d_in[2];
    const float* wk  = (const float*)d_in[3];
    const float* bnk = (const float*)d_in[4];
    const float* wv  = (const float*)d_in[5];
    const float* bnv = (const float*)d_in[6];
    const float* wp  = (const float*)d_in[7];
    const float* bnp = (const float*)d_in[8];
    float* out = (float*)d_out;
    (void)in_sizes; (void)n_in; (void)out_size; (void)ws_size;

    char* ws = (char*)d_ws;
    size_t off = 0;
    auto alloc = [&](size_t bytes) {
        void* p = ws + off;
        off = (off + bytes + 255) & ~(size_t)255;
        return p;
    };
    // --- region A: dead after gemm_qkv; reused as xxT_h (needs >= 33.56 MB) ---
    _Float16* xT_hi = (_Float16*)alloc((size_t)16 * 1024 * 384 * 2);   // 12.58 MB
    _Float16* xT_lo = (_Float16*)alloc((size_t)16 * 1024 * 384 * 2);   // 12.58 MB
    _Float16* wqk_h = (_Float16*)alloc((size_t)512 * 384 * 2);
    _Float16* wv_h  = (_Float16*)alloc((size_t)1024 * 384 * 2);
    alloc((size_t)8 * 1024 * 1024);                                     // pad region A to > 33.56 MB
    _Float16* xxT_h = (_Float16*)d_ws;                                  // alias over region A
    // --- live buffers ---
    _Float16* wp_h  = (_Float16*)alloc((size_t)384 * 1024 * 2);
    float*    s_qkv = (float*)alloc(1536 * 4);
    float*    t_qkv = (float*)alloc(1536 * 4);
    float*    s_p   = (float*)alloc(384 * 4);
    float*    t_p   = (float*)alloc(384 * 4);
    _Float16* qT_h  = (_Float16*)alloc((size_t)16 * 8 * 1024 * 32 * 2); // 8.39 MB
    _Float16* kT_h  = (_Float16*)alloc((size_t)16 * 8 * 1024 * 32 * 2); // 8.39 MB
    _Float16* vbuf  = (_Float16*)alloc((size_t)16 * 1024 * 1024 * 2);   // 33.55 MB
    _Float16* xxT_l = (_Float16*)alloc((size_t)16 * 1024 * 1024 * 2);   // 33.55 MB

    prep<<<dim3(6, 16, 17), dim3(256), 0, stream>>>(
        x, wq, wk, wv, wp, bnq, bnk, bnv, bnp,
        xT_hi, xT_lo, wqk_h, wv_h, wp_h, s_qkv, t_qkv, s_p, t_p);

    gemm_qkv<<<dim3(12, 8, 16), dim3(256), 0, stream>>>(
        wqk_h, wv_h, xT_hi, xT_lo, s_qkv, t_qkv,
        qT_h, kT_h, vbuf);

    attn<<<dim3(128, 8), dim3(256), 0, stream>>>(qT_h, kT_h, vbuf, xxT_h, xxT_l);

    gemm_out<<<dim3(3, 16, 16), dim3(256), 0, stream>>>(wp_h, xxT_h, s_p, t_p, out);
}

// Round 16
// 277.618 us; speedup vs baseline: 1.0219x; 1.0219x over previous
//
#include <hip/hip_runtime.h>

typedef _Float16 f16x8 __attribute__((ext_vector_type(8)));
typedef _Float16 f16x4 __attribute__((ext_vector_type(4)));
typedef __fp16 h16x2 __attribute__((ext_vector_type(2)));
typedef float f32x4 __attribute__((ext_vector_type(4)));
typedef float f32x16 __attribute__((ext_vector_type(16)));

#define BN_EPS 1e-5f
#define SQRT32 5.656854249492381f
#define LOG2E  1.4426950408889634f

typedef const __attribute__((address_space(1))) void* gas_p;
typedef __attribute__((address_space(3))) void* las_p;

// ---------------------------------------------------------------- prep (merged)
// z<16: x [b][c=384][n] fp32 -> xT_hi/lo [b][n][c] fp16 planes (transpose+split).
// z==16: weight conversion + BN affine fold. (wqk lo plane not needed: the
// w-lo term's score contribution is ~5e-4 relative -- measured safe.)
__global__ __launch_bounds__(256) void prep(
    const float* __restrict__ x,
    const float* __restrict__ wq, const float* __restrict__ wk,
    const float* __restrict__ wv, const float* __restrict__ wp,
    const float* __restrict__ bnq, const float* __restrict__ bnk,
    const float* __restrict__ bnv, const float* __restrict__ bnp,
    _Float16* __restrict__ xT_hi, _Float16* __restrict__ xT_lo,
    _Float16* __restrict__ wqk_h,
    _Float16* __restrict__ wv_h,  _Float16* __restrict__ wp_h,
    float* __restrict__ s_qkv, float* __restrict__ t_qkv,
    float* __restrict__ s_p,   float* __restrict__ t_p)
{
    __shared__ float Tx[64][65];
    const int t = threadIdx.x;
    if (blockIdx.z < 16) {
        const int ct = blockIdx.x, nt = blockIdx.y, b = blockIdx.z;
        const int c0 = ct * 64, n0 = nt * 64;
        {
            int tr = t >> 4, tc = (t & 15) * 4;
            #pragma unroll
            for (int p = 0; p < 4; p++) {
                int r = tr + p * 16;
                float4 v = *(const float4*)(x + ((size_t)(b * 384 + c0 + r)) * 1024 + n0 + tc);
                Tx[r][tc + 0] = v.x; Tx[r][tc + 1] = v.y; Tx[r][tc + 2] = v.z; Tx[r][tc + 3] = v.w;
            }
        }
        __syncthreads();
        {
            int nn = t >> 2, cc = (t & 3) * 16;
            f16x8 h0, h1, l0, l1;
            #pragma unroll
            for (int i = 0; i < 8; i++) {
                float v = Tx[cc + i][nn];
                _Float16 hh = (_Float16)v;
                h0[i] = hh; l0[i] = (_Float16)(v - (float)hh);
            }
            #pragma unroll
            for (int i = 0; i < 8; i++) {
                float v = Tx[cc + 8 + i][nn];
                _Float16 hh = (_Float16)v;
                h1[i] = hh; l1[i] = (_Float16)(v - (float)hh);
            }
            size_t o = ((size_t)(b * 1024 + n0 + nn)) * 384 + c0 + cc;
            *(f16x8*)(xT_hi + o) = h0; *(f16x8*)(xT_hi + o + 8) = h1;
            *(f16x8*)(xT_lo + o) = l0; *(f16x8*)(xT_lo + o + 8) = l1;
        }
    } else {
        const int NQK = 512 * 384, NV = 1024 * 384, NP = 384 * 1024;
        int tid = (blockIdx.y * 6 + blockIdx.x) * 256 + t;       // 0..24575
        for (int i = tid; i < NQK + NV + NP; i += 24576) {
            if (i < NQK) {
                int o = i / 384, c = i - o * 384;
                float v = (o < 256) ? wq[o * 384 + c] : wk[(o - 256) * 384 + c];
                wqk_h[i] = (_Float16)v;
            } else if (i < NQK + NV) {
                wv_h[i - NQK] = (_Float16)wv[i - NQK];
            } else {
                wp_h[i - NQK - NV] = (_Float16)wp[i - NQK - NV];
            }
        }
        if (tid < 1536) {
            int i = tid;
            float g, be, m, v;
            if (i < 256)      { int o = i;       g = bnq[o]; be = bnq[256 + o];  m = bnq[512 + o];  v = bnq[768 + o]; }
            else if (i < 512) { int o = i - 256; g = bnk[o]; be = bnk[256 + o];  m = bnk[512 + o];  v = bnk[768 + o]; }
            else              { int o = i - 512; g = bnv[o]; be = bnv[1024 + o]; m = bnv[2048 + o]; v = bnv[3072 + o]; }
            float s = g * rsqrtf(v + BN_EPS);
            float tt = be - m * s;
            // fold /scale (= *sqrt(kd)) AND log2(e) (exp2 softmax) into Q's affine
            if (i < 256) { s *= SQRT32 * LOG2E; tt *= SQRT32 * LOG2E; }
            s_qkv[i] = s; t_qkv[i] = tt;
        } else if (tid < 1536 + 384) {
            int o = tid - 1536;
            float g = bnp[o], be = bnp[384 + o], m = bnp[768 + o], v = bnp[1152 + o];
            float s = g * rsqrtf(v + BN_EPS);
            s_p[o] = s; t_p[o] = be - m * s;
        }
    }
}

// ---------------------------------------------------------------- gemm_qkv
// m97-style staging; vectorized epilogues.
// bx<4 (Q/K): 2-term (w_h*x_h + w_h*x_lo; w-lo dropped -- tiny contribution).
// Q stored hi-plane only (verified round 14); K stored hi/lo (K-lo is the
// EXPENSIVE plane: folded sqrt(32)*log2e in Q makes |Q|*deltaK ~8x |K|*deltaQ).
// bx>=4 (V): 1-term f16 -> PV-permuted vbuf.
__global__ __launch_bounds__(256, 2) void gemm_qkv(
    const _Float16* __restrict__ wqk_h,
    const _Float16* __restrict__ wv_h,
    const _Float16* __restrict__ xT_hi, const _Float16* __restrict__ xT_lo,
    const float* __restrict__ S, const float* __restrict__ T,
    _Float16* __restrict__ qT_h,
    _Float16* __restrict__ kT_h, _Float16* __restrict__ kT_l,
    _Float16* __restrict__ vbuf)
{
    __shared__ __align__(16) _Float16 As_h[128 * 64];   // 16 KB each
    __shared__ __align__(16) _Float16 Bs_h[128 * 64];
    __shared__ __align__(16) _Float16 Bs_l[128 * 64];
    const int t = threadIdx.x, lane = t & 63, w = t >> 6;
    const int wr = w >> 1, wc = w & 1, l16 = lane & 15, lq = lane >> 4;
    const int bx = blockIdx.x, n0 = blockIdx.y * 128, b = blockIdx.z;
    const bool isv = bx >= 4;
    const int o0 = isv ? (bx - 4) * 128 : bx * 128;
    const _Float16* __restrict__ Ah = isv ? wv_h : wqk_h;

    f32x4 acc[4][4] = {};

    for (int kb = 0; kb < 384; kb += 64) {
        __syncthreads();
        // stage via global_load_lds: LDS[row][s] = global[row][s^(row&7)]
        #pragma unroll
        for (int p = 0; p < 4; p++) {
            int g = t + p * 256, row = g >> 3, s = g & 7;
            int col = ((s ^ (row & 7)) * 8);
            __builtin_amdgcn_global_load_lds(
                (gas_p)(const void*)(Ah + (size_t)(o0 + row) * 384 + kb + col),
                (las_p)(void*)&As_h[(p * 256 + w * 64) * 8], 16, 0, 0);
        }
        #pragma unroll
        for (int p = 0; p < 4; p++) {
            int g = t + p * 256, row = g >> 3, s = g & 7;
            int col = ((s ^ (row & 7)) * 8);
            __builtin_amdgcn_global_load_lds(
                (gas_p)(const void*)(xT_hi + ((size_t)(b * 1024) + n0 + row) * 384 + kb + col),
                (las_p)(void*)&Bs_h[(p * 256 + w * 64) * 8], 16, 0, 0);
        }
        if (!isv) {
            #pragma unroll
            for (int p = 0; p < 4; p++) {
                int g = t + p * 256, row = g >> 3, s = g & 7;
                int col = ((s ^ (row & 7)) * 8);
                __builtin_amdgcn_global_load_lds(
                    (gas_p)(const void*)(xT_lo + ((size_t)(b * 1024) + n0 + row) * 384 + kb + col),
                    (las_p)(void*)&Bs_l[(p * 256 + w * 64) * 8], 16, 0, 0);
            }
        }
        __syncthreads();   // drains DMA (vmcnt 0) + joins waves

        if (!isv) {
            // A = w tiles (o rows), B = x tiles (n cols) -> D[o][n]
            #pragma unroll
            for (int kk = 0; kk < 2; kk++) {
                const int sl = ((kk * 4 + lq) ^ (l16 & 7)) * 8;
                f16x8 awh[4], bxh[4], bxl[4];
                #pragma unroll
                for (int i = 0; i < 4; i++)
                    awh[i] = *(const f16x8*)(&As_h[(wr * 64 + i * 16 + l16) * 64 + sl]);
                #pragma unroll
                for (int j = 0; j < 4; j++) {
                    int row = wc * 64 + j * 16 + l16;
                    bxh[j] = *(const f16x8*)(&Bs_h[row * 64 + sl]);
                    bxl[j] = *(const f16x8*)(&Bs_l[row * 64 + sl]);
                }
                #pragma unroll
                for (int i = 0; i < 4; i++)
                    #pragma unroll
                    for (int j = 0; j < 4; j++) {
                        acc[i][j] = __builtin_amdgcn_mfma_f32_16x16x32_f16(awh[i], bxh[j], acc[i][j], 0, 0, 0);
                        acc[i][j] = __builtin_amdgcn_mfma_f32_16x16x32_f16(awh[i], bxl[j], acc[i][j], 0, 0, 0);
                    }
            }
        } else {
            // A = x tiles (n rows), B = wv tiles (o cols) -> D[n][o]
            #pragma unroll
            for (int kk = 0; kk < 2; kk++) {
                const int sl = ((kk * 4 + lq) ^ (l16 & 7)) * 8;
                f16x8 axh[4], bwv[4];
                #pragma unroll
                for (int i = 0; i < 4; i++)
                    axh[i] = *(const f16x8*)(&Bs_h[(wr * 64 + i * 16 + l16) * 64 + sl]);
                #pragma unroll
                for (int j = 0; j < 4; j++)
                    bwv[j] = *(const f16x8*)(&As_h[(wc * 64 + j * 16 + l16) * 64 + sl]);
                #pragma unroll
                for (int i = 0; i < 4; i++)
                    #pragma unroll
                    for (int j = 0; j < 4; j++)
                        acc[i][j] = __builtin_amdgcn_mfma_f32_16x16x32_f16(axh[i], bwv[j], acc[i][j], 0, 0, 0);
            }
        }
    }

    if (!isv) {
        // D[o][n]: lane holds o = o0+wr*64+i*16+lq*4+r (4 consecutive), n fixed.
        #pragma unroll
        for (int i = 0; i < 4; i++) {
            int ob = o0 + wr * 64 + i * 16 + lq * 4;
            float4 sc4 = *(const float4*)(S + ob);
            float4 sh4 = *(const float4*)(T + ob);
            #pragma unroll
            for (int j = 0; j < 4; j++) {
                int n = n0 + wc * 64 + j * 16 + l16;
                f16x4 hv, lv;
                #pragma unroll
                for (int r = 0; r < 4; r++) {
                    float v = acc[i][j][r] * ((const float*)&sc4)[r] + ((const float*)&sh4)[r];
                    _Float16 hh = (_Float16)v;
                    hv[r] = hh; lv[r] = (_Float16)(v - (float)hh);
                }
                if (ob < 256) {
                    size_t idx = (((size_t)(b * 8) + (ob >> 5)) * 1024 + n) * 32 + (ob & 31);
                    *(f16x4*)(qT_h + idx) = hv;       // Q: hi plane only
                } else {
                    int oo = ob - 256;
                    int hd = oo >> 5, c = oo & 31;
                    int f = ((n >> 5) & 1) * 2 + (c >> 4);           // (sub, kh)
                    size_t idx = ((((size_t)(b * 8 + hd) * 16 + (n >> 6)) * 4 + f) * 64
                                  + ((c >> 3) & 1) * 32 + (n & 31)) * 8 + (c & 7);
                    *(f16x4*)(kT_h + idx) = hv;
                    *(f16x4*)(kT_l + idx) = lv;
                }
            }
        }
    } else {
        // D[n][o]: lane holds n (4 consecutive). PV-fragment permutation:
        // k=i*16+lq*4+r -> ep=i*16+(lq&1)*8+(lq>>1)*4+r (consecutive in r).
        #pragma unroll
        for (int i = 0; i < 4; i++) {
            int epb = i * 16 + (lq & 1) * 8 + (lq >> 1) * 4;
            int nhi = n0 + wr * 64;                       // n & ~63
            #pragma unroll
            for (int j = 0; j < 4; j++) {
                int o = o0 + wc * 64 + j * 16 + l16;
                float sc = S[512 + o], sh = T[512 + o];
                f16x4 vv;
                #pragma unroll
                for (int r = 0; r < 4; r++)
                    vv[r] = (_Float16)(acc[i][j][r] * sc + sh);
                *(f16x4*)(vbuf + ((size_t)(b * 1024) + o) * 1024 + nhi + epb) = vv;
            }
        }
    }
}

// ---------------------------------------------------------------- attn
// EXACT round-14 verified attn (102.7 us measured): one-tile-deferred PV,
// V triple-buffered, K hi/lo double-buffered via global_load_lds, Q hi-plane
// only (qk4), defer-max THR=8, max3 row reduction.
__device__ __forceinline__ f32x16 qk4(f16x8 kh0, f16x8 kl0, f16x8 kh1, f16x8 kl1,
                                      f16x8 qh0, f16x8 qh1) {
    f32x16 c = {};
    c = __builtin_amdgcn_mfma_f32_32x32x16_f16(kh0, qh0, c, 0, 0, 0);
    c = __builtin_amdgcn_mfma_f32_32x32x16_f16(kl0, qh0, c, 0, 0, 0);
    c = __builtin_amdgcn_mfma_f32_32x32x16_f16(kh1, qh1, c, 0, 0, 0);
    c = __builtin_amdgcn_mfma_f32_32x32x16_f16(kl1, qh1, c, 0, 0, 0);
    return c;
}

__global__ __launch_bounds__(256, 2) void attn(
    const _Float16* __restrict__ qT_h,
    const _Float16* __restrict__ kT_h, const _Float16* __restrict__ kT_l,
    const _Float16* __restrict__ vbuf,
    _Float16* __restrict__ xxT_h, _Float16* __restrict__ xxT_l)
{
    __shared__ __align__(16) _Float16 Vs[3][128 * 64];   // 48 KB (triple)
    __shared__ __align__(16) _Float16 Ksh[2][2048];      // 8 KB
    __shared__ __align__(16) _Float16 Ksl[2][2048];      // 8 KB
    const int t = threadIdx.x, lane = t & 63, w = t >> 6;
    const int L = lane & 31, hl = lane >> 5;
    const int bh = blockIdx.x, qt = blockIdx.y;
    const int b = bh >> 3, h = bh & 7;
    const size_t vbase = ((size_t)(b * 1024) + h * 128) * 1024;

    // Q B-frags (hi plane only); once per block
    f16x8 bq_h[2];
    {
        int q = qt * 128 + w * 32 + L;
        #pragma unroll
        for (int kh = 0; kh < 2; kh++) {
            size_t base = ((size_t)(bh * 1024) + q) * 32 + kh * 16 + hl * 8;
            bq_h[kh] = *(const f16x8*)(qT_h + base);
        }
    }

    f32x16 o_acc[4] = {};
    float m_st = -INFINITY, l_st = 0.f;
    f16x8 pf[4];        // P(kt-1), consumed one iteration later

    #define DMA_TILE(vb, kb, kt_)                                                  \
        {                                                                          \
            size_t ktb = (size_t)(bh * 16 + (kt_)) * 2048 + (size_t)t * 8;         \
            __builtin_amdgcn_global_load_lds((gas_p)(const void*)(kT_h + ktb),     \
                                             (las_p)(void*)&Ksh[kb][w * 512], 16, 0, 0); \
            __builtin_amdgcn_global_load_lds((gas_p)(const void*)(kT_l + ktb),     \
                                             (las_p)(void*)&Ksl[kb][w * 512], 16, 0, 0); \
            _Pragma("unroll")                                                      \
            for (int p = 0; p < 4; p++) {                                          \
                int g2 = t + p * 256;                                              \
                int d = g2 >> 3;                                                   \
                int kcg = (g2 & 7) ^ (d & 7);                                      \
                const _Float16* src = vbuf + vbase + (size_t)d * 1024              \
                                      + (kt_) * 64 + kcg * 8;                      \
                _Float16* dst = &Vs[vb][(p * 256 + w * 64) * 8];                   \
                __builtin_amdgcn_global_load_lds((gas_p)(const void*)src,          \
                                                 (las_p)(void*)dst, 16, 0, 0);     \
            }                                                                      \
        }

    DMA_TILE(0, 0, 0)
    __syncthreads();

    for (int kt = 0; kt < 16; kt++) {
        const int kcur = kt & 1;
        const int vprv = (kt + 2) % 3;       // buffer holding tile kt-1

        if (kt < 15) DMA_TILE((kt + 1) % 3, kcur ^ 1, kt + 1)

        // K frags from LDS (lgkmcnt only -- DMA stays in flight)
        const _Float16* khp = &Ksh[kcur][lane * 8];
        const _Float16* klp = &Ksl[kcur][lane * 8];
        f16x8 K0h = *(const f16x8*)(khp);
        f16x8 K1h = *(const f16x8*)(khp + 512);
        f16x8 K2h = *(const f16x8*)(khp + 1024);
        f16x8 K3h = *(const f16x8*)(khp + 1536);
        f16x8 K0l = *(const f16x8*)(klp);
        f16x8 K1l = *(const f16x8*)(klp + 512);
        f16x8 K2l = *(const f16x8*)(klp + 1024);
        f16x8 K3l = *(const f16x8*)(klp + 1536);

        __builtin_amdgcn_s_setprio(1);
        f32x16 c0 = qk4(K0h, K0l, K1h, K1l, bq_h[0], bq_h[1]);
        f32x16 c1 = qk4(K2h, K2l, K3h, K3l, bq_h[0], bq_h[1]);
        __builtin_amdgcn_s_setprio(0);

        // ---- PV(kt-1): independent of c0/c1, fills QK's latency shadow ----
        if (kt) {
            __builtin_amdgcn_s_setprio(1);
            #pragma unroll
            for (int s = 0; s < 4; s++) {
                int cp = (2 * s + hl) ^ (L & 7);
                #pragma unroll
                for (int dt = 0; dt < 4; dt++) {
                    f16x8 avp = *(const f16x8*)(&Vs[vprv][(dt * 32 + L) * 64 + cp * 8]);
                    o_acc[dt] = __builtin_amdgcn_mfma_f32_32x32x16_f16(avp, pf[s], o_acc[dt], 0, 0, 0);
                }
            }
            __builtin_amdgcn_s_setprio(0);
        }

        // ---- softmax(kt): overlaps PV's MFMA execution ----
        // row-max via max3 fusion (fmaxf(fmaxf(a,b),c) -> v_max3_f32)
        #define EL(e) ((e) < 16 ? c0[e] : c1[(e) - 16])
        float t1[11];
        #pragma unroll
        for (int g = 0; g < 10; g++)
            t1[g] = fmaxf(fmaxf(EL(3 * g), EL(3 * g + 1)), EL(3 * g + 2));
        t1[10] = fmaxf(EL(30), EL(31));
        #undef EL
        float t2a = fmaxf(fmaxf(t1[0], t1[1]), t1[2]);
        float t2b = fmaxf(fmaxf(t1[3], t1[4]), t1[5]);
        float t2c = fmaxf(fmaxf(t1[6], t1[7]), t1[8]);
        float t2d = fmaxf(t1[9], t1[10]);
        float mx0 = fmaxf(fmaxf(t2a, t2b), fmaxf(t2c, t2d));
        float mx = fmaxf(mx0, __shfl_xor(mx0, 32, 64));

        // defer-max: only rescale when the row max grows by > 8 (p <= 2^8 in f16)
        if (__any(mx > m_st + 8.f)) {
            float mnew = fmaxf(m_st, mx);
            float a = exp2f(m_st - mnew);
            l_st *= a;
            #pragma unroll
            for (int dt = 0; dt < 4; dt++)
                #pragma unroll
                for (int i = 0; i < 16; i++) o_acc[dt][i] *= a;
            m_st = mnew;
        }

        // exp -> packed f16 (cvt_pkrtz), partial-sum trees; store into pf for
        // consumption NEXT iteration
        float rs = 0.f;
        #pragma unroll
        for (int s = 0; s < 4; s++) {
            float pv[8];
            #pragma unroll
            for (int j = 0; j < 8; j++) {
                float cv = (s < 2) ? c0[(s & 1) * 8 + j] : c1[(s & 1) * 8 + j];
                pv[j] = exp2f(cv - m_st);
            }
            rs += ((pv[0] + pv[1]) + (pv[2] + pv[3])) + ((pv[4] + pv[5]) + (pv[6] + pv[7]));
            union { f16x8 v; h16x2 hh[4]; } u;
            #pragma unroll
            for (int j = 0; j < 4; j++)
                u.hh[j] = __builtin_amdgcn_cvt_pkrtz(pv[2 * j], pv[2 * j + 1]);
            pf[s] = u.v;
        }
        l_st += rs;

        if (kt < 15) __syncthreads();   // drains this iter's DMA + joins waves
    }
    #undef DMA_TILE

    // epilogue PV(15): tile 15 lives in Vs[15 % 3 == 0]
    {
        __builtin_amdgcn_s_setprio(1);
        #pragma unroll
        for (int s = 0; s < 4; s++) {
            int cp = (2 * s + hl) ^ (L & 7);
            #pragma unroll
            for (int dt = 0; dt < 4; dt++) {
                f16x8 avp = *(const f16x8*)(&Vs[0][(dt * 32 + L) * 64 + cp * 8]);
                o_acc[dt] = __builtin_amdgcn_mfma_f32_32x32x16_f16(avp, pf[s], o_acc[dt], 0, 0, 0);
            }
        }
        __builtin_amdgcn_s_setprio(0);
    }

    l_st += __shfl_xor(l_st, 32, 64);

    // epilogue: normalize, split hi/lo, store xxT[b][n=q][d]
    {
        float rl = 1.f / l_st;
        int q = qt * 128 + w * 32 + L;
        #pragma unroll
        for (int dt = 0; dt < 4; dt++) {
            #pragma unroll
            for (int gg = 0; gg < 4; gg++) {
                f16x4 hv, lv;
                #pragma unroll
                for (int rr = 0; rr < 4; rr++) {
                    float v = o_acc[dt][gg * 4 + rr] * rl;
                    _Float16 hh = (_Float16)v;
                    hv[rr] = hh; lv[rr] = (_Float16)(v - (float)hh);
                }
                size_t o = ((size_t)(b * 1024) + q) * 1024 + h * 128 + dt * 32 + gg * 8 + hl * 4;
                *(f16x4*)(xxT_h + o) = hv;
                *(f16x4*)(xxT_l + o) = lv;
            }
        }
    }
}

// ---------------------------------------------------------------- gemm_out
// (unchanged from round 12/14 -- verified pass) 1-term f16 on xx_hi.
__global__ __launch_bounds__(256, 2) void gemm_out(
    const _Float16* __restrict__ wp_h,
    const _Float16* __restrict__ xxT_h,
    const float* __restrict__ S, const float* __restrict__ T,
    float* __restrict__ out)
{
    __shared__ __align__(16) _Float16 As[128 * 64];   // 16 KB (wp, rows o)
    __shared__ __align__(16) _Float16 Bh[64 * 64];    // 8 KB (xx hi, rows n)
    const int t = threadIdx.x, lane = t & 63, w = t >> 6;
    const int wr = w >> 1, wc = w & 1, l16 = lane & 15, lq = lane >> 4;
    const int o0 = blockIdx.x * 128, n0 = blockIdx.y * 64, b = blockIdx.z;

    f32x4 acc[2][4] = {};   // [i: n-subtile][j: o-subtile]

    for (int kb = 0; kb < 1024; kb += 64) {
        __syncthreads();
        #pragma unroll
        for (int p = 0; p < 4; p++) {
            int g = t + p * 256, row = g >> 3, s = g & 7;
            int col = ((s ^ (row & 7)) * 8);
            __builtin_amdgcn_global_load_lds(
                (gas_p)(const void*)(wp_h + (size_t)(o0 + row) * 1024 + kb + col),
                (las_p)(void*)&As[(p * 256 + w * 64) * 8], 16, 0, 0);
        }
        #pragma unroll
        for (int p = 0; p < 2; p++) {
            int g = t + p * 256, row = g >> 3, s = g & 7;
            int col = ((s ^ (row & 7)) * 8);
            size_t src = ((size_t)(b * 1024) + n0 + row) * 1024 + kb + col;
            __builtin_amdgcn_global_load_lds(
                (gas_p)(const void*)(xxT_h + src),
                (las_p)(void*)&Bh[(p * 256 + w * 64) * 8], 16, 0, 0);
        }
        __syncthreads();

        #pragma unroll
        for (int kk = 0; kk < 2; kk++) {
            const int sl = ((kk * 4 + lq) ^ (l16 & 7)) * 8;
            f16x8 axh[2], bw[4];
            #pragma unroll
            for (int i = 0; i < 2; i++)
                axh[i] = *(const f16x8*)(&Bh[(wc * 32 + i * 16 + l16) * 64 + sl]);
            #pragma unroll
            for (int j = 0; j < 4; j++)
                bw[j] = *(const f16x8*)(&As[(wr * 64 + j * 16 + l16) * 64 + sl]);
            #pragma unroll
            for (int i = 0; i < 2; i++)
                #pragma unroll
                for (int j = 0; j < 4; j++)
                    acc[i][j] = __builtin_amdgcn_mfma_f32_16x16x32_f16(axh[i], bw[j], acc[i][j], 0, 0, 0);
        }
    }

    // D[n][o]: n = n0+wc*32+i*16+lq*4+r (consecutive), o = o0+wr*64+j*16+l16.
    #pragma unroll
    for (int i = 0; i < 2; i++) {
        int nb = n0 + wc * 32 + i * 16 + lq * 4;
        #pragma unroll
        for (int j = 0; j < 4; j++) {
            int o = o0 + wr * 64 + j * 16 + l16;
            float sc = S[o], sh = T[o];
            float4 vv;
            vv.x = acc[i][j][0] * sc + sh;
            vv.y = acc[i][j][1] * sc + sh;
            vv.z = acc[i][j][2] * sc + sh;
            vv.w = acc[i][j][3] * sc + sh;
            *(float4*)(out + ((size_t)(b * 384) + o) * 1024 + nb) = vv;
        }
    }
}

// ---------------------------------------------------------------- launch

extern "C" void kernel_launch(void* const* d_in, const int* in_sizes, int n_in,
                              void* d_out, int out_size, void* d_ws, size_t ws_size,
                              hipStream_t stream) {
    const float* x   = (const float*)d_in[0];
    const float* wq  = (const float*)d_in[1];
    const float* bnq = (const float*)d_in[2];
    const float* wk  = (const float*)d_in[3];
    const float* bnk = (const float*)d_in[4];
    const float* wv  = (const float*)d_in[5];
    const float* bnv = (const float*)d_in[6];
    const float* wp  = (const float*)d_in[7];
    const float* bnp = (const float*)d_in[8];
    float* out = (float*)d_out;
    (void)in_sizes; (void)n_in; (void)out_size; (void)ws_size;

    char* ws = (char*)d_ws;
    size_t off = 0;
    auto alloc = [&](size_t bytes) {
        void* p = ws + off;
        off = (off + bytes + 255) & ~(size_t)255;
        return p;
    };
    // --- region A: dead after gemm_qkv; reused as xxT_h (needs >= 33.56 MB) ---
    _Float16* xT_hi = (_Float16*)alloc((size_t)16 * 1024 * 384 * 2);   // 12.58 MB
    _Float16* xT_lo = (_Float16*)alloc((size_t)16 * 1024 * 384 * 2);   // 12.58 MB
    _Float16* wqk_h = (_Float16*)alloc((size_t)512 * 384 * 2);
    _Float16* wv_h  = (_Float16*)alloc((size_t)1024 * 384 * 2);
    alloc((size_t)8 * 1024 * 1024);                                     // pad region A to > 33.56 MB
    _Float16* xxT_h = (_Float16*)d_ws;                                  // alias over region A
    // --- live buffers ---
    _Float16* wp_h  = (_Float16*)alloc((size_t)384 * 1024 * 2);
    float*    s_qkv = (float*)alloc(1536 * 4);
    float*    t_qkv = (float*)alloc(1536 * 4);
    float*    s_p   = (float*)alloc(384 * 4);
    float*    t_p   = (float*)alloc(384 * 4);
    _Float16* qT_h  = (_Float16*)alloc((size_t)16 * 8 * 1024 * 32 * 2); // 8.39 MB
    _Float16* kT_h  = (_Float16*)alloc((size_t)16 * 8 * 1024 * 32 * 2); // 8.39 MB
    _Float16* kT_l  = (_Float16*)alloc((size_t)16 * 8 * 1024 * 32 * 2); // 8.39 MB
    _Float16* vbuf  = (_Float16*)alloc((size_t)16 * 1024 * 1024 * 2);   // 33.55 MB
    _Float16* xxT_l = (_Float16*)alloc((size_t)16 * 1024 * 1024 * 2);   // 33.55 MB

    prep<<<dim3(6, 16, 17), dim3(256), 0, stream>>>(
        x, wq, wk, wv, wp, bnq, bnk, bnv, bnp,
        xT_hi, xT_lo, wqk_h, wv_h, wp_h, s_qkv, t_qkv, s_p, t_p);

    gemm_qkv<<<dim3(12, 8, 16), dim3(256), 0, stream>>>(
        wqk_h, wv_h, xT_hi, xT_lo, s_qkv, t_qkv,
        qT_h, kT_h, kT_l, vbuf);

    attn<<<dim3(128, 8), dim3(256), 0, stream>>>(qT_h, kT_h, kT_l, vbuf, xxT_h, xxT_l);

    gemm_out<<<dim3(3, 16, 16), dim3(256), 0, stream>>>(wp_h, xxT_h, s_p, t_p, out);
}

// Round 17
// 268.948 us; speedup vs baseline: 1.0549x; 1.0322x over previous
//
#include <hip/hip_runtime.h>

typedef _Float16 f16x8 __attribute__((ext_vector_type(8)));
typedef _Float16 f16x4 __attribute__((ext_vector_type(4)));
typedef __fp16 h16x2 __attribute__((ext_vector_type(2)));
typedef float f32x4 __attribute__((ext_vector_type(4)));
typedef float f32x16 __attribute__((ext_vector_type(16)));

#define BN_EPS 1e-5f
#define SQRT32 5.656854249492381f
#define LOG2E  1.4426950408889634f

typedef const __attribute__((address_space(1))) void* gas_p;
typedef __attribute__((address_space(3))) void* las_p;

// ---------------------------------------------------------------- prep (merged)
// z<16: x [b][c=384][n] fp32 -> xT_hi/lo [b][n][c] fp16 planes (transpose+split).
// z==16: weight conversion + BN affine fold.
__global__ __launch_bounds__(256) void prep(
    const float* __restrict__ x,
    const float* __restrict__ wq, const float* __restrict__ wk,
    const float* __restrict__ wv, const float* __restrict__ wp,
    const float* __restrict__ bnq, const float* __restrict__ bnk,
    const float* __restrict__ bnv, const float* __restrict__ bnp,
    _Float16* __restrict__ xT_hi, _Float16* __restrict__ xT_lo,
    _Float16* __restrict__ wqk_h,
    _Float16* __restrict__ wv_h,  _Float16* __restrict__ wp_h,
    float* __restrict__ s_qkv, float* __restrict__ t_qkv,
    float* __restrict__ s_p,   float* __restrict__ t_p)
{
    __shared__ float Tx[64][65];
    const int t = threadIdx.x;
    if (blockIdx.z < 16) {
        const int ct = blockIdx.x, nt = blockIdx.y, b = blockIdx.z;
        const int c0 = ct * 64, n0 = nt * 64;
        {
            int tr = t >> 4, tc = (t & 15) * 4;
            #pragma unroll
            for (int p = 0; p < 4; p++) {
                int r = tr + p * 16;
                float4 v = *(const float4*)(x + ((size_t)(b * 384 + c0 + r)) * 1024 + n0 + tc);
                Tx[r][tc + 0] = v.x; Tx[r][tc + 1] = v.y; Tx[r][tc + 2] = v.z; Tx[r][tc + 3] = v.w;
            }
        }
        __syncthreads();
        {
            int nn = t >> 2, cc = (t & 3) * 16;
            f16x8 h0, h1, l0, l1;
            #pragma unroll
            for (int i = 0; i < 8; i++) {
                float v = Tx[cc + i][nn];
                _Float16 hh = (_Float16)v;
                h0[i] = hh; l0[i] = (_Float16)(v - (float)hh);
            }
            #pragma unroll
            for (int i = 0; i < 8; i++) {
                float v = Tx[cc + 8 + i][nn];
                _Float16 hh = (_Float16)v;
                h1[i] = hh; l1[i] = (_Float16)(v - (float)hh);
            }
            size_t o = ((size_t)(b * 1024 + n0 + nn)) * 384 + c0 + cc;
            *(f16x8*)(xT_hi + o) = h0; *(f16x8*)(xT_hi + o + 8) = h1;
            *(f16x8*)(xT_lo + o) = l0; *(f16x8*)(xT_lo + o + 8) = l1;
        }
    } else {
        const int NQK = 512 * 384, NV = 1024 * 384, NP = 384 * 1024;
        int tid = (blockIdx.y * 6 + blockIdx.x) * 256 + t;       // 0..24575
        for (int i = tid; i < NQK + NV + NP; i += 24576) {
            if (i < NQK) {
                int o = i / 384, c = i - o * 384;
                float v = (o < 256) ? wq[o * 384 + c] : wk[(o - 256) * 384 + c];
                wqk_h[i] = (_Float16)v;
            } else if (i < NQK + NV) {
                wv_h[i - NQK] = (_Float16)wv[i - NQK];
            } else {
                wp_h[i - NQK - NV] = (_Float16)wp[i - NQK - NV];
            }
        }
        if (tid < 1536) {
            int i = tid;
            float g, be, m, v;
            if (i < 256)      { int o = i;       g = bnq[o]; be = bnq[256 + o];  m = bnq[512 + o];  v = bnq[768 + o]; }
            else if (i < 512) { int o = i - 256; g = bnk[o]; be = bnk[256 + o];  m = bnk[512 + o];  v = bnk[768 + o]; }
            else              { int o = i - 512; g = bnv[o]; be = bnv[1024 + o]; m = bnv[2048 + o]; v = bnv[3072 + o]; }
            float s = g * rsqrtf(v + BN_EPS);
            float tt = be - m * s;
            // fold /scale (= *sqrt(kd)) AND log2(e) (exp2 softmax) into Q's affine
            if (i < 256) { s *= SQRT32 * LOG2E; tt *= SQRT32 * LOG2E; }
            s_qkv[i] = s; t_qkv[i] = tt;
        } else if (tid < 1536 + 384) {
            int o = tid - 1536;
            float g = bnp[o], be = bnp[384 + o], m = bnp[768 + o], v = bnp[1152 + o];
            float s = g * rsqrtf(v + BN_EPS);
            s_p[o] = s; t_p[o] = be - m * s;
        }
    }
}

// ---------------------------------------------------------------- gemm_qkv
// (round-16 verified) m97-style staging; vectorized epilogues.
// bx<4 (Q/K): 2-term (w_h*x_h + w_h*x_lo). Q hi-plane only; K hi/lo (K-lo is
// the expensive plane: folded sqrt(32)*log2e in Q makes |Q|*dK ~8x |K|*dQ).
// bx>=4 (V): 1-term f16 -> PV-permuted vbuf.
__global__ __launch_bounds__(256, 2) void gemm_qkv(
    const _Float16* __restrict__ wqk_h,
    const _Float16* __restrict__ wv_h,
    const _Float16* __restrict__ xT_hi, const _Float16* __restrict__ xT_lo,
    const float* __restrict__ S, const float* __restrict__ T,
    _Float16* __restrict__ qT_h,
    _Float16* __restrict__ kT_h, _Float16* __restrict__ kT_l,
    _Float16* __restrict__ vbuf)
{
    __shared__ __align__(16) _Float16 As_h[128 * 64];   // 16 KB each
    __shared__ __align__(16) _Float16 Bs_h[128 * 64];
    __shared__ __align__(16) _Float16 Bs_l[128 * 64];
    const int t = threadIdx.x, lane = t & 63, w = t >> 6;
    const int wr = w >> 1, wc = w & 1, l16 = lane & 15, lq = lane >> 4;
    const int bx = blockIdx.x, n0 = blockIdx.y * 128, b = blockIdx.z;
    const bool isv = bx >= 4;
    const int o0 = isv ? (bx - 4) * 128 : bx * 128;
    const _Float16* __restrict__ Ah = isv ? wv_h : wqk_h;

    f32x4 acc[4][4] = {};

    for (int kb = 0; kb < 384; kb += 64) {
        __syncthreads();
        // stage via global_load_lds: LDS[row][s] = global[row][s^(row&7)]
        #pragma unroll
        for (int p = 0; p < 4; p++) {
            int g = t + p * 256, row = g >> 3, s = g & 7;
            int col = ((s ^ (row & 7)) * 8);
            __builtin_amdgcn_global_load_lds(
                (gas_p)(const void*)(Ah + (size_t)(o0 + row) * 384 + kb + col),
                (las_p)(void*)&As_h[(p * 256 + w * 64) * 8], 16, 0, 0);
        }
        #pragma unroll
        for (int p = 0; p < 4; p++) {
            int g = t + p * 256, row = g >> 3, s = g & 7;
            int col = ((s ^ (row & 7)) * 8);
            __builtin_amdgcn_global_load_lds(
                (gas_p)(const void*)(xT_hi + ((size_t)(b * 1024) + n0 + row) * 384 + kb + col),
                (las_p)(void*)&Bs_h[(p * 256 + w * 64) * 8], 16, 0, 0);
        }
        if (!isv) {
            #pragma unroll
            for (int p = 0; p < 4; p++) {
                int g = t + p * 256, row = g >> 3, s = g & 7;
                int col = ((s ^ (row & 7)) * 8);
                __builtin_amdgcn_global_load_lds(
                    (gas_p)(const void*)(xT_lo + ((size_t)(b * 1024) + n0 + row) * 384 + kb + col),
                    (las_p)(void*)&Bs_l[(p * 256 + w * 64) * 8], 16, 0, 0);
            }
        }
        __syncthreads();   // drains DMA (vmcnt 0) + joins waves

        if (!isv) {
            // A = w tiles (o rows), B = x tiles (n cols) -> D[o][n]
            #pragma unroll
            for (int kk = 0; kk < 2; kk++) {
                const int sl = ((kk * 4 + lq) ^ (l16 & 7)) * 8;
                f16x8 awh[4], bxh[4], bxl[4];
                #pragma unroll
                for (int i = 0; i < 4; i++)
                    awh[i] = *(const f16x8*)(&As_h[(wr * 64 + i * 16 + l16) * 64 + sl]);
                #pragma unroll
                for (int j = 0; j < 4; j++) {
                    int row = wc * 64 + j * 16 + l16;
                    bxh[j] = *(const f16x8*)(&Bs_h[row * 64 + sl]);
                    bxl[j] = *(const f16x8*)(&Bs_l[row * 64 + sl]);
                }
                #pragma unroll
                for (int i = 0; i < 4; i++)
                    #pragma unroll
                    for (int j = 0; j < 4; j++) {
                        acc[i][j] = __builtin_amdgcn_mfma_f32_16x16x32_f16(awh[i], bxh[j], acc[i][j], 0, 0, 0);
                        acc[i][j] = __builtin_amdgcn_mfma_f32_16x16x32_f16(awh[i], bxl[j], acc[i][j], 0, 0, 0);
                    }
            }
        } else {
            // A = x tiles (n rows), B = wv tiles (o cols) -> D[n][o]
            #pragma unroll
            for (int kk = 0; kk < 2; kk++) {
                const int sl = ((kk * 4 + lq) ^ (l16 & 7)) * 8;
                f16x8 axh[4], bwv[4];
                #pragma unroll
                for (int i = 0; i < 4; i++)
                    axh[i] = *(const f16x8*)(&Bs_h[(wr * 64 + i * 16 + l16) * 64 + sl]);
                #pragma unroll
                for (int j = 0; j < 4; j++)
                    bwv[j] = *(const f16x8*)(&As_h[(wc * 64 + j * 16 + l16) * 64 + sl]);
                #pragma unroll
                for (int i = 0; i < 4; i++)
                    #pragma unroll
                    for (int j = 0; j < 4; j++)
                        acc[i][j] = __builtin_amdgcn_mfma_f32_16x16x32_f16(axh[i], bwv[j], acc[i][j], 0, 0, 0);
            }
        }
    }

    if (!isv) {
        // D[o][n]: lane holds o = o0+wr*64+i*16+lq*4+r (4 consecutive), n fixed.
        #pragma unroll
        for (int i = 0; i < 4; i++) {
            int ob = o0 + wr * 64 + i * 16 + lq * 4;
            float4 sc4 = *(const float4*)(S + ob);
            float4 sh4 = *(const float4*)(T + ob);
            #pragma unroll
            for (int j = 0; j < 4; j++) {
                int n = n0 + wc * 64 + j * 16 + l16;
                f16x4 hv, lv;
                #pragma unroll
                for (int r = 0; r < 4; r++) {
                    float v = acc[i][j][r] * ((const float*)&sc4)[r] + ((const float*)&sh4)[r];
                    _Float16 hh = (_Float16)v;
                    hv[r] = hh; lv[r] = (_Float16)(v - (float)hh);
                }
                if (ob < 256) {
                    size_t idx = (((size_t)(b * 8) + (ob >> 5)) * 1024 + n) * 32 + (ob & 31);
                    *(f16x4*)(qT_h + idx) = hv;       // Q: hi plane only
                } else {
                    int oo = ob - 256;
                    int hd = oo >> 5, c = oo & 31;
                    int f = ((n >> 5) & 1) * 2 + (c >> 4);           // (sub, kh)
                    size_t idx = ((((size_t)(b * 8 + hd) * 16 + (n >> 6)) * 4 + f) * 64
                                  + ((c >> 3) & 1) * 32 + (n & 31)) * 8 + (c & 7);
                    *(f16x4*)(kT_h + idx) = hv;
                    *(f16x4*)(kT_l + idx) = lv;
                }
            }
        }
    } else {
        // D[n][o]: lane holds n (4 consecutive). PV-fragment permutation:
        // k=i*16+lq*4+r -> ep=i*16+(lq&1)*8+(lq>>1)*4+r (consecutive in r).
        #pragma unroll
        for (int i = 0; i < 4; i++) {
            int epb = i * 16 + (lq & 1) * 8 + (lq >> 1) * 4;
            int nhi = n0 + wr * 64;                       // n & ~63
            #pragma unroll
            for (int j = 0; j < 4; j++) {
                int o = o0 + wc * 64 + j * 16 + l16;
                float sc = S[512 + o], sh = T[512 + o];
                f16x4 vv;
                #pragma unroll
                for (int r = 0; r < 4; r++)
                    vv[r] = (_Float16)(acc[i][j][r] * sc + sh);
                *(f16x4*)(vbuf + ((size_t)(b * 1024) + o) * 1024 + nhi + epb) = vv;
            }
        }
    }
}

// ---------------------------------------------------------------- attn
// Round-14/16 verified structure; ONLY change: xxT_l (DEAD since round 12 --
// gemm_out reads only xxT_h) is no longer computed or written. Halves the
// epilogue VALU and attn's write traffic (67 -> 33.5 MB nominal; removes the
// prime victim of the observed 4x write amplification).
__device__ __forceinline__ f32x16 qk4(f16x8 kh0, f16x8 kl0, f16x8 kh1, f16x8 kl1,
                                      f16x8 qh0, f16x8 qh1) {
    f32x16 c = {};
    c = __builtin_amdgcn_mfma_f32_32x32x16_f16(kh0, qh0, c, 0, 0, 0);
    c = __builtin_amdgcn_mfma_f32_32x32x16_f16(kl0, qh0, c, 0, 0, 0);
    c = __builtin_amdgcn_mfma_f32_32x32x16_f16(kh1, qh1, c, 0, 0, 0);
    c = __builtin_amdgcn_mfma_f32_32x32x16_f16(kl1, qh1, c, 0, 0, 0);
    return c;
}

__global__ __launch_bounds__(256, 2) void attn(
    const _Float16* __restrict__ qT_h,
    const _Float16* __restrict__ kT_h, const _Float16* __restrict__ kT_l,
    const _Float16* __restrict__ vbuf,
    _Float16* __restrict__ xxT_h)
{
    __shared__ __align__(16) _Float16 Vs[3][128 * 64];   // 48 KB (triple)
    __shared__ __align__(16) _Float16 Ksh[2][2048];      // 8 KB
    __shared__ __align__(16) _Float16 Ksl[2][2048];      // 8 KB
    const int t = threadIdx.x, lane = t & 63, w = t >> 6;
    const int L = lane & 31, hl = lane >> 5;
    const int bh = blockIdx.x, qt = blockIdx.y;
    const int b = bh >> 3, h = bh & 7;
    const size_t vbase = ((size_t)(b * 1024) + h * 128) * 1024;

    // Q B-frags (hi plane only); once per block
    f16x8 bq_h[2];
    {
        int q = qt * 128 + w * 32 + L;
        #pragma unroll
        for (int kh = 0; kh < 2; kh++) {
            size_t base = ((size_t)(bh * 1024) + q) * 32 + kh * 16 + hl * 8;
            bq_h[kh] = *(const f16x8*)(qT_h + base);
        }
    }

    f32x16 o_acc[4] = {};
    float m_st = -INFINITY, l_st = 0.f;
    f16x8 pf[4];        // P(kt-1), consumed one iteration later

    #define DMA_TILE(vb, kb, kt_)                                                  \
        {                                                                          \
            size_t ktb = (size_t)(bh * 16 + (kt_)) * 2048 + (size_t)t * 8;         \
            __builtin_amdgcn_global_load_lds((gas_p)(const void*)(kT_h + ktb),     \
                                             (las_p)(void*)&Ksh[kb][w * 512], 16, 0, 0); \
            __builtin_amdgcn_global_load_lds((gas_p)(const void*)(kT_l + ktb),     \
                                             (las_p)(void*)&Ksl[kb][w * 512], 16, 0, 0); \
            _Pragma("unroll")                                                      \
            for (int p = 0; p < 4; p++) {                                          \
                int g2 = t + p * 256;                                              \
                int d = g2 >> 3;                                                   \
                int kcg = (g2 & 7) ^ (d & 7);                                      \
                const _Float16* src = vbuf + vbase + (size_t)d * 1024              \
                                      + (kt_) * 64 + kcg * 8;                      \
                _Float16* dst = &Vs[vb][(p * 256 + w * 64) * 8];                   \
                __builtin_amdgcn_global_load_lds((gas_p)(const void*)src,          \
                                                 (las_p)(void*)dst, 16, 0, 0);     \
            }                                                                      \
        }

    DMA_TILE(0, 0, 0)
    __syncthreads();

    for (int kt = 0; kt < 16; kt++) {
        const int kcur = kt & 1;
        const int vprv = (kt + 2) % 3;       // buffer holding tile kt-1

        if (kt < 15) DMA_TILE((kt + 1) % 3, kcur ^ 1, kt + 1)

        // K frags from LDS (lgkmcnt only -- DMA stays in flight)
        const _Float16* khp = &Ksh[kcur][lane * 8];
        const _Float16* klp = &Ksl[kcur][lane * 8];
        f16x8 K0h = *(const f16x8*)(khp);
        f16x8 K1h = *(const f16x8*)(khp + 512);
        f16x8 K2h = *(const f16x8*)(khp + 1024);
        f16x8 K3h = *(const f16x8*)(khp + 1536);
        f16x8 K0l = *(const f16x8*)(klp);
        f16x8 K1l = *(const f16x8*)(klp + 512);
        f16x8 K2l = *(const f16x8*)(klp + 1024);
        f16x8 K3l = *(const f16x8*)(klp + 1536);

        __builtin_amdgcn_s_setprio(1);
        f32x16 c0 = qk4(K0h, K0l, K1h, K1l, bq_h[0], bq_h[1]);
        f32x16 c1 = qk4(K2h, K2l, K3h, K3l, bq_h[0], bq_h[1]);
        __builtin_amdgcn_s_setprio(0);

        // ---- PV(kt-1): independent of c0/c1, fills QK's latency shadow ----
        if (kt) {
            __builtin_amdgcn_s_setprio(1);
            #pragma unroll
            for (int s = 0; s < 4; s++) {
                int cp = (2 * s + hl) ^ (L & 7);
                #pragma unroll
                for (int dt = 0; dt < 4; dt++) {
                    f16x8 avp = *(const f16x8*)(&Vs[vprv][(dt * 32 + L) * 64 + cp * 8]);
                    o_acc[dt] = __builtin_amdgcn_mfma_f32_32x32x16_f16(avp, pf[s], o_acc[dt], 0, 0, 0);
                }
            }
            __builtin_amdgcn_s_setprio(0);
        }

        // ---- softmax(kt): overlaps PV's MFMA execution ----
        // row-max via max3 fusion (fmaxf(fmaxf(a,b),c) -> v_max3_f32)
        #define EL(e) ((e) < 16 ? c0[e] : c1[(e) - 16])
        float t1[11];
        #pragma unroll
        for (int g = 0; g < 10; g++)
            t1[g] = fmaxf(fmaxf(EL(3 * g), EL(3 * g + 1)), EL(3 * g + 2));
        t1[10] = fmaxf(EL(30), EL(31));
        #undef EL
        float t2a = fmaxf(fmaxf(t1[0], t1[1]), t1[2]);
        float t2b = fmaxf(fmaxf(t1[3], t1[4]), t1[5]);
        float t2c = fmaxf(fmaxf(t1[6], t1[7]), t1[8]);
        float t2d = fmaxf(t1[9], t1[10]);
        float mx0 = fmaxf(fmaxf(t2a, t2b), fmaxf(t2c, t2d));
        float mx = fmaxf(mx0, __shfl_xor(mx0, 32, 64));

        // defer-max: only rescale when the row max grows by > 8 (p <= 2^8 in f16)
        if (__any(mx > m_st + 8.f)) {
            float mnew = fmaxf(m_st, mx);
            float a = exp2f(m_st - mnew);
            l_st *= a;
            #pragma unroll
            for (int dt = 0; dt < 4; dt++)
                #pragma unroll
                for (int i = 0; i < 16; i++) o_acc[dt][i] *= a;
            m_st = mnew;
        }

        // exp -> packed f16 (cvt_pkrtz), partial-sum trees; store into pf for
        // consumption NEXT iteration
        float rs = 0.f;
        #pragma unroll
        for (int s = 0; s < 4; s++) {
            float pv[8];
            #pragma unroll
            for (int j = 0; j < 8; j++) {
                float cv = (s < 2) ? c0[(s & 1) * 8 + j] : c1[(s & 1) * 8 + j];
                pv[j] = exp2f(cv - m_st);
            }
            rs += ((pv[0] + pv[1]) + (pv[2] + pv[3])) + ((pv[4] + pv[5]) + (pv[6] + pv[7]));
            union { f16x8 v; h16x2 hh[4]; } u;
            #pragma unroll
            for (int j = 0; j < 4; j++)
                u.hh[j] = __builtin_amdgcn_cvt_pkrtz(pv[2 * j], pv[2 * j + 1]);
            pf[s] = u.v;
        }
        l_st += rs;

        if (kt < 15) __syncthreads();   // drains this iter's DMA + joins waves
    }
    #undef DMA_TILE

    // epilogue PV(15): tile 15 lives in Vs[15 % 3 == 0]
    {
        __builtin_amdgcn_s_setprio(1);
        #pragma unroll
        for (int s = 0; s < 4; s++) {
            int cp = (2 * s + hl) ^ (L & 7);
            #pragma unroll
            for (int dt = 0; dt < 4; dt++) {
                f16x8 avp = *(const f16x8*)(&Vs[0][(dt * 32 + L) * 64 + cp * 8]);
                o_acc[dt] = __builtin_amdgcn_mfma_f32_32x32x16_f16(avp, pf[s], o_acc[dt], 0, 0, 0);
            }
        }
        __builtin_amdgcn_s_setprio(0);
    }

    l_st += __shfl_xor(l_st, 32, 64);

    // epilogue: normalize, store xxT_h only (xxT_l was dead -- never read)
    {
        float rl = 1.f / l_st;
        int q = qt * 128 + w * 32 + L;
        #pragma unroll
        for (int dt = 0; dt < 4; dt++) {
            #pragma unroll
            for (int gg = 0; gg < 4; gg++) {
                f16x4 hv;
                #pragma unroll
                for (int rr = 0; rr < 4; rr++)
                    hv[rr] = (_Float16)(o_acc[dt][gg * 4 + rr] * rl);
                size_t o = ((size_t)(b * 1024) + q) * 1024 + h * 128 + dt * 32 + gg * 8 + hl * 4;
                *(f16x4*)(xxT_h + o) = hv;
            }
        }
    }
}

// ---------------------------------------------------------------- gemm_out
// (unchanged from round 12/14/16 -- verified pass) 1-term f16 on xx_hi.
__global__ __launch_bounds__(256, 2) void gemm_out(
    const _Float16* __restrict__ wp_h,
    const _Float16* __restrict__ xxT_h,
    const float* __restrict__ S, const float* __restrict__ T,
    float* __restrict__ out)
{
    __shared__ __align__(16) _Float16 As[128 * 64];   // 16 KB (wp, rows o)
    __shared__ __align__(16) _Float16 Bh[64 * 64];    // 8 KB (xx hi, rows n)
    const int t = threadIdx.x, lane = t & 63, w = t >> 6;
    const int wr = w >> 1, wc = w & 1, l16 = lane & 15, lq = lane >> 4;
    const int o0 = blockIdx.x * 128, n0 = blockIdx.y * 64, b = blockIdx.z;

    f32x4 acc[2][4] = {};   // [i: n-subtile][j: o-subtile]

    for (int kb = 0; kb < 1024; kb += 64) {
        __syncthreads();
        #pragma unroll
        for (int p = 0; p < 4; p++) {
            int g = t + p * 256, row = g >> 3, s = g & 7;
            int col = ((s ^ (row & 7)) * 8);
            __builtin_amdgcn_global_load_lds(
                (gas_p)(const void*)(wp_h + (size_t)(o0 + row) * 1024 + kb + col),
                (las_p)(void*)&As[(p * 256 + w * 64) * 8], 16, 0, 0);
        }
        #pragma unroll
        for (int p = 0; p < 2; p++) {
            int g = t + p * 256, row = g >> 3, s = g & 7;
            int col = ((s ^ (row & 7)) * 8);
            size_t src = ((size_t)(b * 1024) + n0 + row) * 1024 + kb + col;
            __builtin_amdgcn_global_load_lds(
                (gas_p)(const void*)(xxT_h + src),
                (las_p)(void*)&Bh[(p * 256 + w * 64) * 8], 16, 0, 0);
        }
        __syncthreads();

        #pragma unroll
        for (int kk = 0; kk < 2; kk++) {
            const int sl = ((kk * 4 + lq) ^ (l16 & 7)) * 8;
            f16x8 axh[2], bw[4];
            #pragma unroll
            for (int i = 0; i < 2; i++)
                axh[i] = *(const f16x8*)(&Bh[(wc * 32 + i * 16 + l16) * 64 + sl]);
            #pragma unroll
            for (int j = 0; j < 4; j++)
                bw[j] = *(const f16x8*)(&As[(wr * 64 + j * 16 + l16) * 64 + sl]);
            #pragma unroll
            for (int i = 0; i < 2; i++)
                #pragma unroll
                for (int j = 0; j < 4; j++)
                    acc[i][j] = __builtin_amdgcn_mfma_f32_16x16x32_f16(axh[i], bw[j], acc[i][j], 0, 0, 0);
        }
    }

    // D[n][o]: n = n0+wc*32+i*16+lq*4+r (consecutive), o = o0+wr*64+j*16+l16.
    #pragma unroll
    for (int i = 0; i < 2; i++) {
        int nb = n0 + wc * 32 + i * 16 + lq * 4;
        #pragma unroll
        for (int j = 0; j < 4; j++) {
            int o = o0 + wr * 64 + j * 16 + l16;
            float sc = S[o], sh = T[o];
            float4 vv;
            vv.x = acc[i][j][0] * sc + sh;
            vv.y = acc[i][j][1] * sc + sh;
            vv.z = acc[i][j][2] * sc + sh;
            vv.w = acc[i][j][3] * sc + sh;
            *(float4*)(out + ((size_t)(b * 384) + o) * 1024 + nb) = vv;
        }
    }
}

// ---------------------------------------------------------------- launch

extern "C" void kernel_launch(void* const* d_in, const int* in_sizes, int n_in,
                              void* d_out, int out_size, void* d_ws, size_t ws_size,
                              hipStream_t stream) {
    const float* x   = (const float*)d_in[0];
    const float* wq  = (const float*)d_in[1];
    const float* bnq = (const float*)d_in[2];
    const float* wk  = (const float*)d_in[3];
    const float* bnk = (const float*)d_in[4];
    const float* wv  = (const float*)d_in[5];
    const float* bnv = (const float*)d_in[6];
    const float* wp  = (const float*)d_in[7];
    const float* bnp = (const float*)d_in[8];
    float* out = (float*)d_out;
    (void)in_sizes; (void)n_in; (void)out_size; (void)ws_size;

    char* ws = (char*)d_ws;
    size_t off = 0;
    auto alloc = [&](size_t bytes) {
        void* p = ws + off;
        off = (off + bytes + 255) & ~(size_t)255;
        return p;
    };
    // --- region A: dead after gemm_qkv; reused as xxT_h (needs >= 33.56 MB) ---
    _Float16* xT_hi = (_Float16*)alloc((size_t)16 * 1024 * 384 * 2);   // 12.58 MB
    _Float16* xT_lo = (_Float16*)alloc((size_t)16 * 1024 * 384 * 2);   // 12.58 MB
    _Float16* wqk_h = (_Float16*)alloc((size_t)512 * 384 * 2);
    _Float16* wv_h  = (_Float16*)alloc((size_t)1024 * 384 * 2);
    alloc((size_t)8 * 1024 * 1024);                                     // pad region A to > 33.56 MB
    _Float16* xxT_h = (_Float16*)d_ws;                                  // alias over region A
    // --- live buffers ---
    _Float16* wp_h  = (_Float16*)alloc((size_t)384 * 1024 * 2);
    float*    s_qkv = (float*)alloc(1536 * 4);
    float*    t_qkv = (float*)alloc(1536 * 4);
    float*    s_p   = (float*)alloc(384 * 4);
    float*    t_p   = (float*)alloc(384 * 4);
    _Float16* qT_h  = (_Float16*)alloc((size_t)16 * 8 * 1024 * 32 * 2); // 8.39 MB
    _Float16* kT_h  = (_Float16*)alloc((size_t)16 * 8 * 1024 * 32 * 2); // 8.39 MB
    _Float16* kT_l  = (_Float16*)alloc((size_t)16 * 8 * 1024 * 32 * 2); // 8.39 MB
    _Float16* vbuf  = (_Float16*)alloc((size_t)16 * 1024 * 1024 * 2);   // 33.55 MB

    prep<<<dim3(6, 16, 17), dim3(256), 0, stream>>>(
        x, wq, wk, wv, wp, bnq, bnk, bnv, bnp,
        xT_hi, xT_lo, wqk_h, wv_h, wp_h, s_qkv, t_qkv, s_p, t_p);

    gemm_qkv<<<dim3(12, 8, 16), dim3(256), 0, stream>>>(
        wqk_h, wv_h, xT_hi, xT_lo, s_qkv, t_qkv,
        qT_h, kT_h, kT_l, vbuf);

    attn<<<dim3(128, 8), dim3(256), 0, stream>>>(qT_h, kT_h, kT_l, vbuf, xxT_h);

    gemm_out<<<dim3(3, 16, 16), dim3(256), 0, stream>>>(wp_h, xxT_h, s_p, t_p, out);
}

// Round 19
// 258.542 us; speedup vs baseline: 1.0973x; 1.0402x over previous
//
#include <hip/hip_runtime.h>

typedef _Float16 f16x8 __attribute__((ext_vector_type(8)));
typedef _Float16 f16x4 __attribute__((ext_vector_type(4)));
typedef __fp16 h16x2 __attribute__((ext_vector_type(2)));
typedef float f32x4 __attribute__((ext_vector_type(4)));
typedef float f32x16 __attribute__((ext_vector_type(16)));

#define BN_EPS 1e-5f
#define SQRT32 5.656854249492381f
#define LOG2E  1.4426950408889634f

typedef const __attribute__((address_space(1))) void* gas_p;
typedef __attribute__((address_space(3))) void* las_p;

// ---------------------------------------------------------------- prep (merged)
// z<16: x [b][c=384][n] fp32 -> xT_hi/lo [b][n][c] fp16 planes (transpose+split).
// z==16: weight conversion + BN affine fold.
__global__ __launch_bounds__(256) void prep(
    const float* __restrict__ x,
    const float* __restrict__ wq, const float* __restrict__ wk,
    const float* __restrict__ wv, const float* __restrict__ wp,
    const float* __restrict__ bnq, const float* __restrict__ bnk,
    const float* __restrict__ bnv, const float* __restrict__ bnp,
    _Float16* __restrict__ xT_hi, _Float16* __restrict__ xT_lo,
    _Float16* __restrict__ wqk_h,
    _Float16* __restrict__ wv_h,  _Float16* __restrict__ wp_h,
    float* __restrict__ s_qkv, float* __restrict__ t_qkv,
    float* __restrict__ s_p,   float* __restrict__ t_p)
{
    __shared__ float Tx[64][65];
    const int t = threadIdx.x;
    if (blockIdx.z < 16) {
        const int ct = blockIdx.x, nt = blockIdx.y, b = blockIdx.z;
        const int c0 = ct * 64, n0 = nt * 64;
        {
            int tr = t >> 4, tc = (t & 15) * 4;
            #pragma unroll
            for (int p = 0; p < 4; p++) {
                int r = tr + p * 16;
                float4 v = *(const float4*)(x + ((size_t)(b * 384 + c0 + r)) * 1024 + n0 + tc);
                Tx[r][tc + 0] = v.x; Tx[r][tc + 1] = v.y; Tx[r][tc + 2] = v.z; Tx[r][tc + 3] = v.w;
            }
        }
        __syncthreads();
        {
            int nn = t >> 2, cc = (t & 3) * 16;
            f16x8 h0, h1, l0, l1;
            #pragma unroll
            for (int i = 0; i < 8; i++) {
                float v = Tx[cc + i][nn];
                _Float16 hh = (_Float16)v;
                h0[i] = hh; l0[i] = (_Float16)(v - (float)hh);
            }
            #pragma unroll
            for (int i = 0; i < 8; i++) {
                float v = Tx[cc + 8 + i][nn];
                _Float16 hh = (_Float16)v;
                h1[i] = hh; l1[i] = (_Float16)(v - (float)hh);
            }
            size_t o = ((size_t)(b * 1024 + n0 + nn)) * 384 + c0 + cc;
            *(f16x8*)(xT_hi + o) = h0; *(f16x8*)(xT_hi + o + 8) = h1;
            *(f16x8*)(xT_lo + o) = l0; *(f16x8*)(xT_lo + o + 8) = l1;
        }
    } else {
        const int NQK = 512 * 384, NV = 1024 * 384, NP = 384 * 1024;
        int tid = (blockIdx.y * 6 + blockIdx.x) * 256 + t;       // 0..24575
        for (int i = tid; i < NQK + NV + NP; i += 24576) {
            if (i < NQK) {
                int o = i / 384, c = i - o * 384;
                float v = (o < 256) ? wq[o * 384 + c] : wk[(o - 256) * 384 + c];
                wqk_h[i] = (_Float16)v;
            } else if (i < NQK + NV) {
                wv_h[i - NQK] = (_Float16)wv[i - NQK];
            } else {
                wp_h[i - NQK - NV] = (_Float16)wp[i - NQK - NV];
            }
        }
        if (tid < 1536) {
            int i = tid;
            float g, be, m, v;
            if (i < 256)      { int o = i;       g = bnq[o]; be = bnq[256 + o];  m = bnq[512 + o];  v = bnq[768 + o]; }
            else if (i < 512) { int o = i - 256; g = bnk[o]; be = bnk[256 + o];  m = bnk[512 + o];  v = bnk[768 + o]; }
            else              { int o = i - 512; g = bnv[o]; be = bnv[1024 + o]; m = bnv[2048 + o]; v = bnv[3072 + o]; }
            float s = g * rsqrtf(v + BN_EPS);
            float tt = be - m * s;
            // fold /scale (= *sqrt(kd)) AND log2(e) (exp2 softmax) into Q's affine
            if (i < 256) { s *= SQRT32 * LOG2E; tt *= SQRT32 * LOG2E; }
            s_qkv[i] = s; t_qkv[i] = tt;
        } else if (tid < 1536 + 384) {
            int o = tid - 1536;
            float g = bnp[o], be = bnp[384 + o], m = bnp[768 + o], v = bnp[1152 + o];
            float s = g * rsqrtf(v + BN_EPS);
            s_p[o] = s; t_p[o] = be - m * s;
        }
    }
}

// ---------------------------------------------------------------- gemm_qkv
// (round-16/17 verified) m97-style staging; vectorized epilogues.
// bx<4 (Q/K): 2-term (w_h*x_h + w_h*x_lo). Q hi-plane only; K hi/lo.
// bx>=4 (V): 1-term f16 -> PV-permuted vbuf.
__global__ __launch_bounds__(256, 2) void gemm_qkv(
    const _Float16* __restrict__ wqk_h,
    const _Float16* __restrict__ wv_h,
    const _Float16* __restrict__ xT_hi, const _Float16* __restrict__ xT_lo,
    const float* __restrict__ S, const float* __restrict__ T,
    _Float16* __restrict__ qT_h,
    _Float16* __restrict__ kT_h, _Float16* __restrict__ kT_l,
    _Float16* __restrict__ vbuf)
{
    __shared__ __align__(16) _Float16 As_h[128 * 64];   // 16 KB each
    __shared__ __align__(16) _Float16 Bs_h[128 * 64];
    __shared__ __align__(16) _Float16 Bs_l[128 * 64];
    const int t = threadIdx.x, lane = t & 63, w = t >> 6;
    const int wr = w >> 1, wc = w & 1, l16 = lane & 15, lq = lane >> 4;
    const int bx = blockIdx.x, n0 = blockIdx.y * 128, b = blockIdx.z;
    const bool isv = bx >= 4;
    const int o0 = isv ? (bx - 4) * 128 : bx * 128;
    const _Float16* __restrict__ Ah = isv ? wv_h : wqk_h;

    f32x4 acc[4][4] = {};

    for (int kb = 0; kb < 384; kb += 64) {
        __syncthreads();
        // stage via global_load_lds: LDS[row][s] = global[row][s^(row&7)]
        #pragma unroll
        for (int p = 0; p < 4; p++) {
            int g = t + p * 256, row = g >> 3, s = g & 7;
            int col = ((s ^ (row & 7)) * 8);
            __builtin_amdgcn_global_load_lds(
                (gas_p)(const void*)(Ah + (size_t)(o0 + row) * 384 + kb + col),
                (las_p)(void*)&As_h[(p * 256 + w * 64) * 8], 16, 0, 0);
        }
        #pragma unroll
        for (int p = 0; p < 4; p++) {
            int g = t + p * 256, row = g >> 3, s = g & 7;
            int col = ((s ^ (row & 7)) * 8);
            __builtin_amdgcn_global_load_lds(
                (gas_p)(const void*)(xT_hi + ((size_t)(b * 1024) + n0 + row) * 384 + kb + col),
                (las_p)(void*)&Bs_h[(p * 256 + w * 64) * 8], 16, 0, 0);
        }
        if (!isv) {
            #pragma unroll
            for (int p = 0; p < 4; p++) {
                int g = t + p * 256, row = g >> 3, s = g & 7;
                int col = ((s ^ (row & 7)) * 8);
                __builtin_amdgcn_global_load_lds(
                    (gas_p)(const void*)(xT_lo + ((size_t)(b * 1024) + n0 + row) * 384 + kb + col),
                    (las_p)(void*)&Bs_l[(p * 256 + w * 64) * 8], 16, 0, 0);
            }
        }
        __syncthreads();   // drains DMA (vmcnt 0) + joins waves

        if (!isv) {
            // A = w tiles (o rows), B = x tiles (n cols) -> D[o][n]
            #pragma unroll
            for (int kk = 0; kk < 2; kk++) {
                const int sl = ((kk * 4 + lq) ^ (l16 & 7)) * 8;
                f16x8 awh[4], bxh[4], bxl[4];
                #pragma unroll
                for (int i = 0; i < 4; i++)
                    awh[i] = *(const f16x8*)(&As_h[(wr * 64 + i * 16 + l16) * 64 + sl]);
                #pragma unroll
                for (int j = 0; j < 4; j++) {
                    int row = wc * 64 + j * 16 + l16;
                    bxh[j] = *(const f16x8*)(&Bs_h[row * 64 + sl]);
                    bxl[j] = *(const f16x8*)(&Bs_l[row * 64 + sl]);
                }
                #pragma unroll
                for (int i = 0; i < 4; i++)
                    #pragma unroll
                    for (int j = 0; j < 4; j++) {
                        acc[i][j] = __builtin_amdgcn_mfma_f32_16x16x32_f16(awh[i], bxh[j], acc[i][j], 0, 0, 0);
                        acc[i][j] = __builtin_amdgcn_mfma_f32_16x16x32_f16(awh[i], bxl[j], acc[i][j], 0, 0, 0);
                    }
            }
        } else {
            // A = x tiles (n rows), B = wv tiles (o cols) -> D[n][o]
            #pragma unroll
            for (int kk = 0; kk < 2; kk++) {
                const int sl = ((kk * 4 + lq) ^ (l16 & 7)) * 8;
                f16x8 axh[4], bwv[4];
                #pragma unroll
                for (int i = 0; i < 4; i++)
                    axh[i] = *(const f16x8*)(&Bs_h[(wr * 64 + i * 16 + l16) * 64 + sl]);
                #pragma unroll
                for (int j = 0; j < 4; j++)
                    bwv[j] = *(const f16x8*)(&As_h[(wc * 64 + j * 16 + l16) * 64 + sl]);
                #pragma unroll
                for (int i = 0; i < 4; i++)
                    #pragma unroll
                    for (int j = 0; j < 4; j++)
                        acc[i][j] = __builtin_amdgcn_mfma_f32_16x16x32_f16(axh[i], bwv[j], acc[i][j], 0, 0, 0);
            }
        }
    }

    if (!isv) {
        // D[o][n]: lane holds o = o0+wr*64+i*16+lq*4+r (4 consecutive), n fixed.
        #pragma unroll
        for (int i = 0; i < 4; i++) {
            int ob = o0 + wr * 64 + i * 16 + lq * 4;
            float4 sc4 = *(const float4*)(S + ob);
            float4 sh4 = *(const float4*)(T + ob);
            #pragma unroll
            for (int j = 0; j < 4; j++) {
                int n = n0 + wc * 64 + j * 16 + l16;
                f16x4 hv, lv;
                #pragma unroll
                for (int r = 0; r < 4; r++) {
                    float v = acc[i][j][r] * ((const float*)&sc4)[r] + ((const float*)&sh4)[r];
                    _Float16 hh = (_Float16)v;
                    hv[r] = hh; lv[r] = (_Float16)(v - (float)hh);
                }
                if (ob < 256) {
                    size_t idx = (((size_t)(b * 8) + (ob >> 5)) * 1024 + n) * 32 + (ob & 31);
                    *(f16x4*)(qT_h + idx) = hv;       // Q: hi plane only
                } else {
                    int oo = ob - 256;
                    int hd = oo >> 5, c = oo & 31;
                    int f = ((n >> 5) & 1) * 2 + (c >> 4);           // (sub, kh)
                    size_t idx = ((((size_t)(b * 8 + hd) * 16 + (n >> 6)) * 4 + f) * 64
                                  + ((c >> 3) & 1) * 32 + (n & 31)) * 8 + (c & 7);
                    *(f16x4*)(kT_h + idx) = hv;
                    *(f16x4*)(kT_l + idx) = lv;
                }
            }
        }
    } else {
        // D[n][o]: lane holds n (4 consecutive). PV-fragment permutation:
        // k=i*16+lq*4+r -> ep=i*16+(lq&1)*8+(lq>>1)*4+r (consecutive in r).
        #pragma unroll
        for (int i = 0; i < 4; i++) {
            int epb = i * 16 + (lq & 1) * 8 + (lq >> 1) * 4;
            int nhi = n0 + wr * 64;                       // n & ~63
            #pragma unroll
            for (int j = 0; j < 4; j++) {
                int o = o0 + wc * 64 + j * 16 + l16;
                float sc = S[512 + o], sh = T[512 + o];
                f16x4 vv;
                #pragma unroll
                for (int r = 0; r < 4; r++)
                    vv[r] = (_Float16)(acc[i][j][r] * sc + sh);
                *(f16x4*)(vbuf + ((size_t)(b * 1024) + o) * 1024 + nhi + epb) = vv;
            }
        }
    }
}

// ---------------------------------------------------------------- attn
// Round-17 verified structure + VALU->MFMA offloads with CORRECTED gate:
// (1) -m folded into the QK accumulator INIT (mInit as the MFMA C operand).
// (2) l via ones-MFMA (lacc[0] = l); deletes the row-sum tree + shfl.
// Gate fix vs round 18 (NaN): kt==0 ALWAYS sets m to the per-row max of
// tile 0 (c -= mx, no rescale of the zero accumulators -- old -INFINITY
// semantics; prevents f16 underflow l=0 -> 1/0*0 = NaN); kt>0 uses
// d = max(mx, 0) so m is MONOTONE (prevents P overflow after a lowered m).
__global__ __launch_bounds__(256, 2) void attn(
    const _Float16* __restrict__ qT_h,
    const _Float16* __restrict__ kT_h, const _Float16* __restrict__ kT_l,
    const _Float16* __restrict__ vbuf,
    _Float16* __restrict__ xxT_h)
{
    __shared__ __align__(16) _Float16 Vs[3][128 * 64];   // 48 KB (triple)
    __shared__ __align__(16) _Float16 Ksh[2][2048];      // 8 KB
    __shared__ __align__(16) _Float16 Ksl[2][2048];      // 8 KB
    const int t = threadIdx.x, lane = t & 63, w = t >> 6;
    const int L = lane & 31, hl = lane >> 5;
    const int bh = blockIdx.x, qt = blockIdx.y;
    const int b = bh >> 3, h = bh & 7;
    const size_t vbase = ((size_t)(b * 1024) + h * 128) * 1024;

    // Q B-frags (hi plane only); once per block
    f16x8 bq_h[2];
    {
        int q = qt * 128 + w * 32 + L;
        #pragma unroll
        for (int kh = 0; kh < 2; kh++) {
            size_t base = ((size_t)(bh * 1024) + q) * 32 + kh * 16 + hl * 8;
            bq_h[kh] = *(const f16x8*)(qT_h + base);
        }
    }

    f32x16 o_acc[4] = {};
    f32x16 lacc = {};          // row-sum accumulator (ones-MFMA); lacc[0] = l
    f32x16 mInit = {};         // broadcast(-m_running); C-operand for QK
    f16x8 ones;
    #pragma unroll
    for (int i = 0; i < 8; i++) ones[i] = (_Float16)1.0f;
    f16x8 pf[4];               // P(kt-1), consumed one iteration later

    #define DMA_TILE(vb, kb, kt_)                                                  \
        {                                                                          \
            size_t ktb = (size_t)(bh * 16 + (kt_)) * 2048 + (size_t)t * 8;         \
            __builtin_amdgcn_global_load_lds((gas_p)(const void*)(kT_h + ktb),     \
                                             (las_p)(void*)&Ksh[kb][w * 512], 16, 0, 0); \
            __builtin_amdgcn_global_load_lds((gas_p)(const void*)(kT_l + ktb),     \
                                             (las_p)(void*)&Ksl[kb][w * 512], 16, 0, 0); \
            _Pragma("unroll")                                                      \
            for (int p = 0; p < 4; p++) {                                          \
                int g2 = t + p * 256;                                              \
                int d = g2 >> 3;                                                   \
                int kcg = (g2 & 7) ^ (d & 7);                                      \
                const _Float16* src = vbuf + vbase + (size_t)d * 1024              \
                                      + (kt_) * 64 + kcg * 8;                      \
                _Float16* dst = &Vs[vb][(p * 256 + w * 64) * 8];                   \
                __builtin_amdgcn_global_load_lds((gas_p)(const void*)src,          \
                                                 (las_p)(void*)dst, 16, 0, 0);     \
            }                                                                      \
        }

    DMA_TILE(0, 0, 0)
    __syncthreads();

    for (int kt = 0; kt < 16; kt++) {
        const int kcur = kt & 1;
        const int vprv = (kt + 2) % 3;       // buffer holding tile kt-1

        if (kt < 15) DMA_TILE((kt + 1) % 3, kcur ^ 1, kt + 1)

        // K frags from LDS (lgkmcnt only -- DMA stays in flight)
        const _Float16* khp = &Ksh[kcur][lane * 8];
        const _Float16* klp = &Ksl[kcur][lane * 8];
        f16x8 K0h = *(const f16x8*)(khp);
        f16x8 K1h = *(const f16x8*)(khp + 512);
        f16x8 K2h = *(const f16x8*)(khp + 1024);
        f16x8 K3h = *(const f16x8*)(khp + 1536);
        f16x8 K0l = *(const f16x8*)(klp);
        f16x8 K1l = *(const f16x8*)(klp + 512);
        f16x8 K2l = *(const f16x8*)(klp + 1024);
        f16x8 K3l = *(const f16x8*)(klp + 1536);

        // QK with C = mInit (= broadcast(-m_old)): c' is pre-subtracted
        __builtin_amdgcn_s_setprio(1);
        f32x16 c0 = __builtin_amdgcn_mfma_f32_32x32x16_f16(K0h, bq_h[0], mInit, 0, 0, 0);
        f32x16 c1 = __builtin_amdgcn_mfma_f32_32x32x16_f16(K2h, bq_h[0], mInit, 0, 0, 0);
        c0 = __builtin_amdgcn_mfma_f32_32x32x16_f16(K0l, bq_h[0], c0, 0, 0, 0);
        c1 = __builtin_amdgcn_mfma_f32_32x32x16_f16(K2l, bq_h[0], c1, 0, 0, 0);
        c0 = __builtin_amdgcn_mfma_f32_32x32x16_f16(K1h, bq_h[1], c0, 0, 0, 0);
        c1 = __builtin_amdgcn_mfma_f32_32x32x16_f16(K3h, bq_h[1], c1, 0, 0, 0);
        c0 = __builtin_amdgcn_mfma_f32_32x32x16_f16(K1l, bq_h[1], c0, 0, 0, 0);
        c1 = __builtin_amdgcn_mfma_f32_32x32x16_f16(K3l, bq_h[1], c1, 0, 0, 0);
        __builtin_amdgcn_s_setprio(0);

        // ---- PV(kt-1) + lacc: independent of c0/c1, fills QK's shadow ----
        if (kt) {
            __builtin_amdgcn_s_setprio(1);
            #pragma unroll
            for (int s = 0; s < 4; s++) {
                int cp = (2 * s + hl) ^ (L & 7);
                #pragma unroll
                for (int dt = 0; dt < 4; dt++) {
                    f16x8 avp = *(const f16x8*)(&Vs[vprv][(dt * 32 + L) * 64 + cp * 8]);
                    o_acc[dt] = __builtin_amdgcn_mfma_f32_32x32x16_f16(avp, pf[s], o_acc[dt], 0, 0, 0);
                }
                lacc = __builtin_amdgcn_mfma_f32_32x32x16_f16(ones, pf[s], lacc, 0, 0, 0);
            }
            __builtin_amdgcn_s_setprio(0);
        }

        // ---- softmax(kt): row-max of c' via max3 fusion ----
        #define EL(e) ((e) < 16 ? c0[e] : c1[(e) - 16])
        float t1[11];
        #pragma unroll
        for (int g = 0; g < 10; g++)
            t1[g] = fmaxf(fmaxf(EL(3 * g), EL(3 * g + 1)), EL(3 * g + 2));
        t1[10] = fmaxf(EL(30), EL(31));
        #undef EL
        float t2a = fmaxf(fmaxf(t1[0], t1[1]), t1[2]);
        float t2b = fmaxf(fmaxf(t1[3], t1[4]), t1[5]);
        float t2c = fmaxf(fmaxf(t1[6], t1[7]), t1[8]);
        float t2d = fmaxf(t1[9], t1[10]);
        float mx0 = fmaxf(fmaxf(t2a, t2b), fmaxf(t2c, t2d));
        float mx = fmaxf(mx0, __shfl_xor(mx0, 32, 64));

        // gate: kt==0 always sets m to tile-0 row max (no rescale of zero
        // accumulators); kt>0 fires on wave-any growth > 8 with monotone m
        if (kt == 0) {
            #pragma unroll
            for (int i = 0; i < 16; i++) { c0[i] -= mx; c1[i] -= mx; mInit[i] -= mx; }
        } else if (__any(mx > 8.f)) {
            float d = fmaxf(mx, 0.f);          // per-lane; m never decreases
            float a = exp2f(-d);               // = 1 for lanes that didn't grow
            #pragma unroll
            for (int i = 0; i < 16; i++) lacc[i] *= a;
            #pragma unroll
            for (int dt = 0; dt < 4; dt++)
                #pragma unroll
                for (int i = 0; i < 16; i++) o_acc[dt][i] *= a;
            #pragma unroll
            for (int i = 0; i < 16; i++) { c0[i] -= d; c1[i] -= d; mInit[i] -= d; }
        }

        // exp -> packed f16 (no subtract in the common path)
        #pragma unroll
        for (int s = 0; s < 4; s++) {
            float pv[8];
            #pragma unroll
            for (int j = 0; j < 8; j++) {
                float cv = (s < 2) ? c0[(s & 1) * 8 + j] : c1[(s & 1) * 8 + j];
                pv[j] = exp2f(cv);
            }
            union { f16x8 v; h16x2 hh[4]; } u;
            #pragma unroll
            for (int j = 0; j < 4; j++)
                u.hh[j] = __builtin_amdgcn_cvt_pkrtz(pv[2 * j], pv[2 * j + 1]);
            pf[s] = u.v;
        }

        if (kt < 15) __syncthreads();   // drains this iter's DMA + joins waves
    }
    #undef DMA_TILE

    // epilogue PV(15) + lacc(15): tile 15 lives in Vs[15 % 3 == 0]
    {
        __builtin_amdgcn_s_setprio(1);
        #pragma unroll
        for (int s = 0; s < 4; s++) {
            int cp = (2 * s + hl) ^ (L & 7);
            #pragma unroll
            for (int dt = 0; dt < 4; dt++) {
                f16x8 avp = *(const f16x8*)(&Vs[0][(dt * 32 + L) * 64 + cp * 8]);
                o_acc[dt] = __builtin_amdgcn_mfma_f32_32x32x16_f16(avp, pf[s], o_acc[dt], 0, 0, 0);
            }
            lacc = __builtin_amdgcn_mfma_f32_32x32x16_f16(ones, pf[s], lacc, 0, 0, 0);
        }
        __builtin_amdgcn_s_setprio(0);
    }

    // epilogue: normalize by lacc[0] (= l for q=L), store xxT_h
    {
        float rl = 1.f / lacc[0];
        int q = qt * 128 + w * 32 + L;
        #pragma unroll
        for (int dt = 0; dt < 4; dt++) {
            #pragma unroll
            for (int gg = 0; gg < 4; gg++) {
                f16x4 hv;
                #pragma unroll
                for (int rr = 0; rr < 4; rr++)
                    hv[rr] = (_Float16)(o_acc[dt][gg * 4 + rr] * rl);
                size_t o = ((size_t)(b * 1024) + q) * 1024 + h * 128 + dt * 32 + gg * 8 + hl * 4;
                *(f16x4*)(xxT_h + o) = hv;
            }
        }
    }
}

// ---------------------------------------------------------------- gemm_out
// (round-17 verified) 1-term f16 on xx_hi.
__global__ __launch_bounds__(256, 2) void gemm_out(
    const _Float16* __restrict__ wp_h,
    const _Float16* __restrict__ xxT_h,
    const float* __restrict__ S, const float* __restrict__ T,
    float* __restrict__ out)
{
    __shared__ __align__(16) _Float16 As[128 * 64];   // 16 KB (wp, rows o)
    __shared__ __align__(16) _Float16 Bh[64 * 64];    // 8 KB (xx hi, rows n)
    const int t = threadIdx.x, lane = t & 63, w = t >> 6;
    const int wr = w >> 1, wc = w & 1, l16 = lane & 15, lq = lane >> 4;
    const int o0 = blockIdx.x * 128, n0 = blockIdx.y * 64, b = blockIdx.z;

    f32x4 acc[2][4] = {};   // [i: n-subtile][j: o-subtile]

    for (int kb = 0; kb < 1024; kb += 64) {
        __syncthreads();
        #pragma unroll
        for (int p = 0; p < 4; p++) {
            int g = t + p * 256, row = g >> 3, s = g & 7;
            int col = ((s ^ (row & 7)) * 8);
            __builtin_amdgcn_global_load_lds(
                (gas_p)(const void*)(wp_h + (size_t)(o0 + row) * 1024 + kb + col),
                (las_p)(void*)&As[(p * 256 + w * 64) * 8], 16, 0, 0);
        }
        #pragma unroll
        for (int p = 0; p < 2; p++) {
            int g = t + p * 256, row = g >> 3, s = g & 7;
            int col = ((s ^ (row & 7)) * 8);
            size_t src = ((size_t)(b * 1024) + n0 + row) * 1024 + kb + col;
            __builtin_amdgcn_global_load_lds(
                (gas_p)(const void*)(xxT_h + src),
                (las_p)(void*)&Bh[(p * 256 + w * 64) * 8], 16, 0, 0);
        }
        __syncthreads();

        #pragma unroll
        for (int kk = 0; kk < 2; kk++) {
            const int sl = ((kk * 4 + lq) ^ (l16 & 7)) * 8;
            f16x8 axh[2], bw[4];
            #pragma unroll
            for (int i = 0; i < 2; i++)
                axh[i] = *(const f16x8*)(&Bh[(wc * 32 + i * 16 + l16) * 64 + sl]);
            #pragma unroll
            for (int j = 0; j < 4; j++)
                bw[j] = *(const f16x8*)(&As[(wr * 64 + j * 16 + l16) * 64 + sl]);
            #pragma unroll
            for (int i = 0; i < 2; i++)
                #pragma unroll
                for (int j = 0; j < 4; j++)
                    acc[i][j] = __builtin_amdgcn_mfma_f32_16x16x32_f16(axh[i], bw[j], acc[i][j], 0, 0, 0);
        }
    }

    // D[n][o]: n = n0+wc*32+i*16+lq*4+r (consecutive), o = o0+wr*64+j*16+l16.
    #pragma unroll
    for (int i = 0; i < 2; i++) {
        int nb = n0 + wc * 32 + i * 16 + lq * 4;
        #pragma unroll
        for (int j = 0; j < 4; j++) {
            int o = o0 + wr * 64 + j * 16 + l16;
            float sc = S[o], sh = T[o];
            float4 vv;
            vv.x = acc[i][j][0] * sc + sh;
            vv.y = acc[i][j][1] * sc + sh;
            vv.z = acc[i][j][2] * sc + sh;
            vv.w = acc[i][j][3] * sc + sh;
            *(float4*)(out + ((size_t)(b * 384) + o) * 1024 + nb) = vv;
        }
    }
}

// ---------------------------------------------------------------- launch

extern "C" void kernel_launch(void* const* d_in, const int* in_sizes, int n_in,
                              void* d_out, int out_size, void* d_ws, size_t ws_size,
                              hipStream_t stream) {
    const float* x   = (const float*)d_in[0];
    const float* wq  = (const float*)d_in[1];
    const float* bnq = (const float*)d_in[2];
    const float* wk  = (const float*)d_in[3];
    const float* bnk = (const float*)d_in[4];
    const float* wv  = (const float*)d_in[5];
    const float* bnv = (const float*)d_in[6];
    const float* wp  = (const float*)d_in[7];
    const float* bnp = (const float*)d_in[8];
    float* out = (float*)d_out;
    (void)in_sizes; (void)n_in; (void)out_size; (void)ws_size;

    char* ws = (char*)d_ws;
    size_t off = 0;
    auto alloc = [&](size_t bytes) {
        void* p = ws + off;
        off = (off + bytes + 255) & ~(size_t)255;
        return p;
    };
    // --- region A: dead after gemm_qkv; reused as xxT_h (needs >= 33.56 MB) ---
    _Float16* xT_hi = (_Float16*)alloc((size_t)16 * 1024 * 384 * 2);   // 12.58 MB
    _Float16* xT_lo = (_Float16*)alloc((size_t)16 * 1024 * 384 * 2);   // 12.58 MB
    _Float16* wqk_h = (_Float16*)alloc((size_t)512 * 384 * 2);
    _Float16* wv_h  = (_Float16*)alloc((size_t)1024 * 384 * 2);
    alloc((size_t)8 * 1024 * 1024);                                     // pad region A to > 33.56 MB
    _Float16* xxT_h = (_Float16*)d_ws;                                  // alias over region A
    // --- live buffers ---
    _Float16* wp_h  = (_Float16*)alloc((size_t)384 * 1024 * 2);
    float*    s_qkv = (float*)alloc(1536 * 4);
    float*    t_qkv = (float*)alloc(1536 * 4);
    float*    s_p   = (float*)alloc(384 * 4);
    float*    t_p   = (float*)alloc(384 * 4);
    _Float16* qT_h  = (_Float16*)alloc((size_t)16 * 8 * 1024 * 32 * 2); // 8.39 MB
    _Float16* kT_h  = (_Float16*)alloc((size_t)16 * 8 * 1024 * 32 * 2); // 8.39 MB
    _Float16* kT_l  = (_Float16*)alloc((size_t)16 * 8 * 1024 * 32 * 2); // 8.39 MB
    _Float16* vbuf  = (_Float16*)alloc((size_t)16 * 1024 * 1024 * 2);   // 33.55 MB

    prep<<<dim3(6, 16, 17), dim3(256), 0, stream>>>(
        x, wq, wk, wv, wp, bnq, bnk, bnv, bnp,
        xT_hi, xT_lo, wqk_h, wv_h, wp_h, s_qkv, t_qkv, s_p, t_p);

    gemm_qkv<<<dim3(12, 8, 16), dim3(256), 0, stream>>>(
        wqk_h, wv_h, xT_hi, xT_lo, s_qkv, t_qkv,
        qT_h, kT_h, kT_l, vbuf);

    attn<<<dim3(128, 8), dim3(256), 0, stream>>>(qT_h, kT_h, kT_l, vbuf, xxT_h);

    gemm_out<<<dim3(3, 16, 16), dim3(256), 0, stream>>>(wp_h, xxT_h, s_p, t_p, out);
}

// Round 20
// 251.781 us; speedup vs baseline: 1.1268x; 1.0269x over previous
//
#include <hip/hip_runtime.h>

typedef _Float16 f16x8 __attribute__((ext_vector_type(8)));
typedef _Float16 f16x4 __attribute__((ext_vector_type(4)));
typedef __fp16 h16x2 __attribute__((ext_vector_type(2)));
typedef float f32x4 __attribute__((ext_vector_type(4)));
typedef float f32x16 __attribute__((ext_vector_type(16)));

#define BN_EPS 1e-5f
#define SQRT32 5.656854249492381f
#define LOG2E  1.4426950408889634f

typedef const __attribute__((address_space(1))) void* gas_p;
typedef __attribute__((address_space(3))) void* las_p;

// ---------------------------------------------------------------- prep (merged)
// z<16: x [b][c=384][n] fp32 -> xT_hi/lo [b][n][c] fp16 planes (transpose+split).
// z==16: weight conversion + BN affine fold.
__global__ __launch_bounds__(256) void prep(
    const float* __restrict__ x,
    const float* __restrict__ wq, const float* __restrict__ wk,
    const float* __restrict__ wv, const float* __restrict__ wp,
    const float* __restrict__ bnq, const float* __restrict__ bnk,
    const float* __restrict__ bnv, const float* __restrict__ bnp,
    _Float16* __restrict__ xT_hi, _Float16* __restrict__ xT_lo,
    _Float16* __restrict__ wqk_h,
    _Float16* __restrict__ wv_h,  _Float16* __restrict__ wp_h,
    float* __restrict__ s_qkv, float* __restrict__ t_qkv,
    float* __restrict__ s_p,   float* __restrict__ t_p)
{
    __shared__ float Tx[64][65];
    const int t = threadIdx.x;
    if (blockIdx.z < 16) {
        const int ct = blockIdx.x, nt = blockIdx.y, b = blockIdx.z;
        const int c0 = ct * 64, n0 = nt * 64;
        {
            int tr = t >> 4, tc = (t & 15) * 4;
            #pragma unroll
            for (int p = 0; p < 4; p++) {
                int r = tr + p * 16;
                float4 v = *(const float4*)(x + ((size_t)(b * 384 + c0 + r)) * 1024 + n0 + tc);
                Tx[r][tc + 0] = v.x; Tx[r][tc + 1] = v.y; Tx[r][tc + 2] = v.z; Tx[r][tc + 3] = v.w;
            }
        }
        __syncthreads();
        {
            int nn = t >> 2, cc = (t & 3) * 16;
            f16x8 h0, h1, l0, l1;
            #pragma unroll
            for (int i = 0; i < 8; i++) {
                float v = Tx[cc + i][nn];
                _Float16 hh = (_Float16)v;
                h0[i] = hh; l0[i] = (_Float16)(v - (float)hh);
            }
            #pragma unroll
            for (int i = 0; i < 8; i++) {
                float v = Tx[cc + 8 + i][nn];
                _Float16 hh = (_Float16)v;
                h1[i] = hh; l1[i] = (_Float16)(v - (float)hh);
            }
            size_t o = ((size_t)(b * 1024 + n0 + nn)) * 384 + c0 + cc;
            *(f16x8*)(xT_hi + o) = h0; *(f16x8*)(xT_hi + o + 8) = h1;
            *(f16x8*)(xT_lo + o) = l0; *(f16x8*)(xT_lo + o + 8) = l1;
        }
    } else {
        const int NQK = 512 * 384, NV = 1024 * 384, NP = 384 * 1024;
        int tid = (blockIdx.y * 6 + blockIdx.x) * 256 + t;       // 0..24575
        for (int i = tid; i < NQK + NV + NP; i += 24576) {
            if (i < NQK) {
                int o = i / 384, c = i - o * 384;
                float v = (o < 256) ? wq[o * 384 + c] : wk[(o - 256) * 384 + c];
                wqk_h[i] = (_Float16)v;
            } else if (i < NQK + NV) {
                wv_h[i - NQK] = (_Float16)wv[i - NQK];
            } else {
                wp_h[i - NQK - NV] = (_Float16)wp[i - NQK - NV];
            }
        }
        if (tid < 1536) {
            int i = tid;
            float g, be, m, v;
            if (i < 256)      { int o = i;       g = bnq[o]; be = bnq[256 + o];  m = bnq[512 + o];  v = bnq[768 + o]; }
            else if (i < 512) { int o = i - 256; g = bnk[o]; be = bnk[256 + o];  m = bnk[512 + o];  v = bnk[768 + o]; }
            else              { int o = i - 512; g = bnv[o]; be = bnv[1024 + o]; m = bnv[2048 + o]; v = bnv[3072 + o]; }
            float s = g * rsqrtf(v + BN_EPS);
            float tt = be - m * s;
            // fold /scale (= *sqrt(kd)) AND log2(e) (exp2 softmax) into Q's affine
            if (i < 256) { s *= SQRT32 * LOG2E; tt *= SQRT32 * LOG2E; }
            s_qkv[i] = s; t_qkv[i] = tt;
        } else if (tid < 1536 + 384) {
            int o = tid - 1536;
            float g = bnp[o], be = bnp[384 + o], m = bnp[768 + o], v = bnp[1152 + o];
            float s = g * rsqrtf(v + BN_EPS);
            s_p[o] = s; t_p[o] = be - m * s;
        }
    }
}

// ---------------------------------------------------------------- gemm_qkv
// m97-style staging; vectorized epilogues.
// bx<2 (Q): 1-term (w_h*x_h) -- Q-side error is non-amplified (measured
//   analog +1.28 in quadrature); skips the x_lo DMA entirely.
// bx 2-3 (K): 2-term (w_h*x_h + w_h*x_lo). K-side is the 8x-amplified plane.
// bx>=4 (V): 1-term f16 -> PV-permuted vbuf.
__global__ __launch_bounds__(256, 2) void gemm_qkv(
    const _Float16* __restrict__ wqk_h,
    const _Float16* __restrict__ wv_h,
    const _Float16* __restrict__ xT_hi, const _Float16* __restrict__ xT_lo,
    const float* __restrict__ S, const float* __restrict__ T,
    _Float16* __restrict__ qT_h,
    _Float16* __restrict__ kT_h, _Float16* __restrict__ kT_l,
    _Float16* __restrict__ vbuf)
{
    __shared__ __align__(16) _Float16 As_h[128 * 64];   // 16 KB each
    __shared__ __align__(16) _Float16 Bs_h[128 * 64];
    __shared__ __align__(16) _Float16 Bs_l[128 * 64];
    const int t = threadIdx.x, lane = t & 63, w = t >> 6;
    const int wr = w >> 1, wc = w & 1, l16 = lane & 15, lq = lane >> 4;
    const int bx = blockIdx.x, n0 = blockIdx.y * 128, b = blockIdx.z;
    const bool isv = bx >= 4;
    const bool isq = bx < 2;                 // Q blocks: o0 < 256
    const int o0 = isv ? (bx - 4) * 128 : bx * 128;
    const _Float16* __restrict__ Ah = isv ? wv_h : wqk_h;

    f32x4 acc[4][4] = {};

    for (int kb = 0; kb < 384; kb += 64) {
        __syncthreads();
        // stage via global_load_lds: LDS[row][s] = global[row][s^(row&7)]
        #pragma unroll
        for (int p = 0; p < 4; p++) {
            int g = t + p * 256, row = g >> 3, s = g & 7;
            int col = ((s ^ (row & 7)) * 8);
            __builtin_amdgcn_global_load_lds(
                (gas_p)(const void*)(Ah + (size_t)(o0 + row) * 384 + kb + col),
                (las_p)(void*)&As_h[(p * 256 + w * 64) * 8], 16, 0, 0);
        }
        #pragma unroll
        for (int p = 0; p < 4; p++) {
            int g = t + p * 256, row = g >> 3, s = g & 7;
            int col = ((s ^ (row & 7)) * 8);
            __builtin_amdgcn_global_load_lds(
                (gas_p)(const void*)(xT_hi + ((size_t)(b * 1024) + n0 + row) * 384 + kb + col),
                (las_p)(void*)&Bs_h[(p * 256 + w * 64) * 8], 16, 0, 0);
        }
        if (!isv && !isq) {                  // K blocks only: stage x_lo
            #pragma unroll
            for (int p = 0; p < 4; p++) {
                int g = t + p * 256, row = g >> 3, s = g & 7;
                int col = ((s ^ (row & 7)) * 8);
                __builtin_amdgcn_global_load_lds(
                    (gas_p)(const void*)(xT_lo + ((size_t)(b * 1024) + n0 + row) * 384 + kb + col),
                    (las_p)(void*)&Bs_l[(p * 256 + w * 64) * 8], 16, 0, 0);
            }
        }
        __syncthreads();   // drains DMA (vmcnt 0) + joins waves

        if (!isv && !isq) {
            // K: A = w tiles (o rows), B = x tiles hi+lo (n cols) -> D[o][n]
            #pragma unroll
            for (int kk = 0; kk < 2; kk++) {
                const int sl = ((kk * 4 + lq) ^ (l16 & 7)) * 8;
                f16x8 awh[4], bxh[4], bxl[4];
                #pragma unroll
                for (int i = 0; i < 4; i++)
                    awh[i] = *(const f16x8*)(&As_h[(wr * 64 + i * 16 + l16) * 64 + sl]);
                #pragma unroll
                for (int j = 0; j < 4; j++) {
                    int row = wc * 64 + j * 16 + l16;
                    bxh[j] = *(const f16x8*)(&Bs_h[row * 64 + sl]);
                    bxl[j] = *(const f16x8*)(&Bs_l[row * 64 + sl]);
                }
                #pragma unroll
                for (int i = 0; i < 4; i++)
                    #pragma unroll
                    for (int j = 0; j < 4; j++) {
                        acc[i][j] = __builtin_amdgcn_mfma_f32_16x16x32_f16(awh[i], bxh[j], acc[i][j], 0, 0, 0);
                        acc[i][j] = __builtin_amdgcn_mfma_f32_16x16x32_f16(awh[i], bxl[j], acc[i][j], 0, 0, 0);
                    }
            }
        } else if (isq) {
            // Q: 1-term, A = w tiles, B = x_hi tiles -> D[o][n]
            #pragma unroll
            for (int kk = 0; kk < 2; kk++) {
                const int sl = ((kk * 4 + lq) ^ (l16 & 7)) * 8;
                f16x8 awh[4], bxh[4];
                #pragma unroll
                for (int i = 0; i < 4; i++)
                    awh[i] = *(const f16x8*)(&As_h[(wr * 64 + i * 16 + l16) * 64 + sl]);
                #pragma unroll
                for (int j = 0; j < 4; j++)
                    bxh[j] = *(const f16x8*)(&Bs_h[(wc * 64 + j * 16 + l16) * 64 + sl]);
                #pragma unroll
                for (int i = 0; i < 4; i++)
                    #pragma unroll
                    for (int j = 0; j < 4; j++)
                        acc[i][j] = __builtin_amdgcn_mfma_f32_16x16x32_f16(awh[i], bxh[j], acc[i][j], 0, 0, 0);
            }
        } else {
            // V: A = x tiles (n rows), B = wv tiles (o cols) -> D[n][o]
            #pragma unroll
            for (int kk = 0; kk < 2; kk++) {
                const int sl = ((kk * 4 + lq) ^ (l16 & 7)) * 8;
                f16x8 axh[4], bwv[4];
                #pragma unroll
                for (int i = 0; i < 4; i++)
                    axh[i] = *(const f16x8*)(&Bs_h[(wr * 64 + i * 16 + l16) * 64 + sl]);
                #pragma unroll
                for (int j = 0; j < 4; j++)
                    bwv[j] = *(const f16x8*)(&As_h[(wc * 64 + j * 16 + l16) * 64 + sl]);
                #pragma unroll
                for (int i = 0; i < 4; i++)
                    #pragma unroll
                    for (int j = 0; j < 4; j++)
                        acc[i][j] = __builtin_amdgcn_mfma_f32_16x16x32_f16(axh[i], bwv[j], acc[i][j], 0, 0, 0);
            }
        }
    }

    if (!isv) {
        // D[o][n]: lane holds o = o0+wr*64+i*16+lq*4+r (4 consecutive), n fixed.
        #pragma unroll
        for (int i = 0; i < 4; i++) {
            int ob = o0 + wr * 64 + i * 16 + lq * 4;
            float4 sc4 = *(const float4*)(S + ob);
            float4 sh4 = *(const float4*)(T + ob);
            #pragma unroll
            for (int j = 0; j < 4; j++) {
                int n = n0 + wc * 64 + j * 16 + l16;
                f16x4 hv, lv;
                #pragma unroll
                for (int r = 0; r < 4; r++) {
                    float v = acc[i][j][r] * ((const float*)&sc4)[r] + ((const float*)&sh4)[r];
                    _Float16 hh = (_Float16)v;
                    hv[r] = hh; lv[r] = (_Float16)(v - (float)hh);
                }
                if (ob < 256) {
                    size_t idx = (((size_t)(b * 8) + (ob >> 5)) * 1024 + n) * 32 + (ob & 31);
                    *(f16x4*)(qT_h + idx) = hv;       // Q: hi plane only
                } else {
                    int oo = ob - 256;
                    int hd = oo >> 5, c = oo & 31;
                    int f = ((n >> 5) & 1) * 2 + (c >> 4);           // (sub, kh)
                    size_t idx = ((((size_t)(b * 8 + hd) * 16 + (n >> 6)) * 4 + f) * 64
                                  + ((c >> 3) & 1) * 32 + (n & 31)) * 8 + (c & 7);
                    *(f16x4*)(kT_h + idx) = hv;
                    *(f16x4*)(kT_l + idx) = lv;
                }
            }
        }
    } else {
        // D[n][o]: lane holds n (4 consecutive). PV-fragment permutation:
        // k=i*16+lq*4+r -> ep=i*16+(lq&1)*8+(lq>>1)*4+r (consecutive in r).
        #pragma unroll
        for (int i = 0; i < 4; i++) {
            int epb = i * 16 + (lq & 1) * 8 + (lq >> 1) * 4;
            int nhi = n0 + wr * 64;                       // n & ~63
            #pragma unroll
            for (int j = 0; j < 4; j++) {
                int o = o0 + wc * 64 + j * 16 + l16;
                float sc = S[512 + o], sh = T[512 + o];
                f16x4 vv;
                #pragma unroll
                for (int r = 0; r < 4; r++)
                    vv[r] = (_Float16)(acc[i][j][r] * sc + sh);
                *(f16x4*)(vbuf + ((size_t)(b * 1024) + o) * 1024 + nhi + epb) = vv;
            }
        }
    }
}

// ---------------------------------------------------------------- attn
// (round-19 verified, 258.5 us total) MFMA-offloaded online softmax:
// -m folded into the QK C-operand (mInit); l via ones-MFMA (lacc[0]);
// kt==0 always rebases m to tile-0 row max; kt>0 monotone defer-max gate.
__global__ __launch_bounds__(256, 2) void attn(
    const _Float16* __restrict__ qT_h,
    const _Float16* __restrict__ kT_h, const _Float16* __restrict__ kT_l,
    const _Float16* __restrict__ vbuf,
    _Float16* __restrict__ xxT_h)
{
    __shared__ __align__(16) _Float16 Vs[3][128 * 64];   // 48 KB (triple)
    __shared__ __align__(16) _Float16 Ksh[2][2048];      // 8 KB
    __shared__ __align__(16) _Float16 Ksl[2][2048];      // 8 KB
    const int t = threadIdx.x, lane = t & 63, w = t >> 6;
    const int L = lane & 31, hl = lane >> 5;
    const int bh = blockIdx.x, qt = blockIdx.y;
    const int b = bh >> 3, h = bh & 7;
    const size_t vbase = ((size_t)(b * 1024) + h * 128) * 1024;

    // Q B-frags (hi plane only); once per block
    f16x8 bq_h[2];
    {
        int q = qt * 128 + w * 32 + L;
        #pragma unroll
        for (int kh = 0; kh < 2; kh++) {
            size_t base = ((size_t)(bh * 1024) + q) * 32 + kh * 16 + hl * 8;
            bq_h[kh] = *(const f16x8*)(qT_h + base);
        }
    }

    f32x16 o_acc[4] = {};
    f32x16 lacc = {};          // row-sum accumulator (ones-MFMA); lacc[0] = l
    f32x16 mInit = {};         // broadcast(-m_running); C-operand for QK
    f16x8 ones;
    #pragma unroll
    for (int i = 0; i < 8; i++) ones[i] = (_Float16)1.0f;
    f16x8 pf[4];               // P(kt-1), consumed one iteration later

    #define DMA_TILE(vb, kb, kt_)                                                  \
        {                                                                          \
            size_t ktb = (size_t)(bh * 16 + (kt_)) * 2048 + (size_t)t * 8;         \
            __builtin_amdgcn_global_load_lds((gas_p)(const void*)(kT_h + ktb),     \
                                             (las_p)(void*)&Ksh[kb][w * 512], 16, 0, 0); \
            __builtin_amdgcn_global_load_lds((gas_p)(const void*)(kT_l + ktb),     \
                                             (las_p)(void*)&Ksl[kb][w * 512], 16, 0, 0); \
            _Pragma("unroll")                                                      \
            for (int p = 0; p < 4; p++) {                                          \
                int g2 = t + p * 256;                                              \
                int d = g2 >> 3;                                                   \
                int kcg = (g2 & 7) ^ (d & 7);                                      \
                const _Float16* src = vbuf + vbase + (size_t)d * 1024              \
                                      + (kt_) * 64 + kcg * 8;                      \
                _Float16* dst = &Vs[vb][(p * 256 + w * 64) * 8];                   \
                __builtin_amdgcn_global_load_lds((gas_p)(const void*)src,          \
                                                 (las_p)(void*)dst, 16, 0, 0);     \
            }                                                                      \
        }

    DMA_TILE(0, 0, 0)
    __syncthreads();

    for (int kt = 0; kt < 16; kt++) {
        const int kcur = kt & 1;
        const int vprv = (kt + 2) % 3;       // buffer holding tile kt-1

        if (kt < 15) DMA_TILE((kt + 1) % 3, kcur ^ 1, kt + 1)

        // K frags from LDS (lgkmcnt only -- DMA stays in flight)
        const _Float16* khp = &Ksh[kcur][lane * 8];
        const _Float16* klp = &Ksl[kcur][lane * 8];
        f16x8 K0h = *(const f16x8*)(khp);
        f16x8 K1h = *(const f16x8*)(khp + 512);
        f16x8 K2h = *(const f16x8*)(khp + 1024);
        f16x8 K3h = *(const f16x8*)(khp + 1536);
        f16x8 K0l = *(const f16x8*)(klp);
        f16x8 K1l = *(const f16x8*)(klp + 512);
        f16x8 K2l = *(const f16x8*)(klp + 1024);
        f16x8 K3l = *(const f16x8*)(klp + 1536);

        // QK with C = mInit (= broadcast(-m_old)): c' is pre-subtracted
        __builtin_amdgcn_s_setprio(1);
        f32x16 c0 = __builtin_amdgcn_mfma_f32_32x32x16_f16(K0h, bq_h[0], mInit, 0, 0, 0);
        f32x16 c1 = __builtin_amdgcn_mfma_f32_32x32x16_f16(K2h, bq_h[0], mInit, 0, 0, 0);
        c0 = __builtin_amdgcn_mfma_f32_32x32x16_f16(K0l, bq_h[0], c0, 0, 0, 0);
        c1 = __builtin_amdgcn_mfma_f32_32x32x16_f16(K2l, bq_h[0], c1, 0, 0, 0);
        c0 = __builtin_amdgcn_mfma_f32_32x32x16_f16(K1h, bq_h[1], c0, 0, 0, 0);
        c1 = __builtin_amdgcn_mfma_f32_32x32x16_f16(K3h, bq_h[1], c1, 0, 0, 0);
        c0 = __builtin_amdgcn_mfma_f32_32x32x16_f16(K1l, bq_h[1], c0, 0, 0, 0);
        c1 = __builtin_amdgcn_mfma_f32_32x32x16_f16(K3l, bq_h[1], c1, 0, 0, 0);
        __builtin_amdgcn_s_setprio(0);

        // ---- PV(kt-1) + lacc: independent of c0/c1, fills QK's shadow ----
        if (kt) {
            __builtin_amdgcn_s_setprio(1);
            #pragma unroll
            for (int s = 0; s < 4; s++) {
                int cp = (2 * s + hl) ^ (L & 7);
                #pragma unroll
                for (int dt = 0; dt < 4; dt++) {
                    f16x8 avp = *(const f16x8*)(&Vs[vprv][(dt * 32 + L) * 64 + cp * 8]);
                    o_acc[dt] = __builtin_amdgcn_mfma_f32_32x32x16_f16(avp, pf[s], o_acc[dt], 0, 0, 0);
                }
                lacc = __builtin_amdgcn_mfma_f32_32x32x16_f16(ones, pf[s], lacc, 0, 0, 0);
            }
            __builtin_amdgcn_s_setprio(0);
        }

        // ---- softmax(kt): row-max of c' via max3 fusion ----
        #define EL(e) ((e) < 16 ? c0[e] : c1[(e) - 16])
        float t1[11];
        #pragma unroll
        for (int g = 0; g < 10; g++)
            t1[g] = fmaxf(fmaxf(EL(3 * g), EL(3 * g + 1)), EL(3 * g + 2));
        t1[10] = fmaxf(EL(30), EL(31));
        #undef EL
        float t2a = fmaxf(fmaxf(t1[0], t1[1]), t1[2]);
        float t2b = fmaxf(fmaxf(t1[3], t1[4]), t1[5]);
        float t2c = fmaxf(fmaxf(t1[6], t1[7]), t1[8]);
        float t2d = fmaxf(t1[9], t1[10]);
        float mx0 = fmaxf(fmaxf(t2a, t2b), fmaxf(t2c, t2d));
        float mx = fmaxf(mx0, __shfl_xor(mx0, 32, 64));

        // gate: kt==0 always sets m to tile-0 row max (no rescale of zero
        // accumulators); kt>0 fires on wave-any growth > 8 with monotone m
        if (kt == 0) {
            #pragma unroll
            for (int i = 0; i < 16; i++) { c0[i] -= mx; c1[i] -= mx; mInit[i] -= mx; }
        } else if (__any(mx > 8.f)) {
            float d = fmaxf(mx, 0.f);          // per-lane; m never decreases
            float a = exp2f(-d);               // = 1 for lanes that didn't grow
            #pragma unroll
            for (int i = 0; i < 16; i++) lacc[i] *= a;
            #pragma unroll
            for (int dt = 0; dt < 4; dt++)
                #pragma unroll
                for (int i = 0; i < 16; i++) o_acc[dt][i] *= a;
            #pragma unroll
            for (int i = 0; i < 16; i++) { c0[i] -= d; c1[i] -= d; mInit[i] -= d; }
        }

        // exp -> packed f16 (no subtract in the common path)
        #pragma unroll
        for (int s = 0; s < 4; s++) {
            float pv[8];
            #pragma unroll
            for (int j = 0; j < 8; j++) {
                float cv = (s < 2) ? c0[(s & 1) * 8 + j] : c1[(s & 1) * 8 + j];
                pv[j] = exp2f(cv);
            }
            union { f16x8 v; h16x2 hh[4]; } u;
            #pragma unroll
            for (int j = 0; j < 4; j++)
                u.hh[j] = __builtin_amdgcn_cvt_pkrtz(pv[2 * j], pv[2 * j + 1]);
            pf[s] = u.v;
        }

        if (kt < 15) __syncthreads();   // drains this iter's DMA + joins waves
    }
    #undef DMA_TILE

    // epilogue PV(15) + lacc(15): tile 15 lives in Vs[15 % 3 == 0]
    {
        __builtin_amdgcn_s_setprio(1);
        #pragma unroll
        for (int s = 0; s < 4; s++) {
            int cp = (2 * s + hl) ^ (L & 7);
            #pragma unroll
            for (int dt = 0; dt < 4; dt++) {
                f16x8 avp = *(const f16x8*)(&Vs[0][(dt * 32 + L) * 64 + cp * 8]);
                o_acc[dt] = __builtin_amdgcn_mfma_f32_32x32x16_f16(avp, pf[s], o_acc[dt], 0, 0, 0);
            }
            lacc = __builtin_amdgcn_mfma_f32_32x32x16_f16(ones, pf[s], lacc, 0, 0, 0);
        }
        __builtin_amdgcn_s_setprio(0);
    }

    // epilogue: normalize by lacc[0] (= l for q=L), store xxT_h
    {
        float rl = 1.f / lacc[0];
        int q = qt * 128 + w * 32 + L;
        #pragma unroll
        for (int dt = 0; dt < 4; dt++) {
            #pragma unroll
            for (int gg = 0; gg < 4; gg++) {
                f16x4 hv;
                #pragma unroll
                for (int rr = 0; rr < 4; rr++)
                    hv[rr] = (_Float16)(o_acc[dt][gg * 4 + rr] * rl);
                size_t o = ((size_t)(b * 1024) + q) * 1024 + h * 128 + dt * 32 + gg * 8 + hl * 4;
                *(f16x4*)(xxT_h + o) = hv;
            }
        }
    }
}

// ---------------------------------------------------------------- gemm_out
// (round-17/19 verified) 1-term f16 on xx_hi.
__global__ __launch_bounds__(256, 2) void gemm_out(
    const _Float16* __restrict__ wp_h,
    const _Float16* __restrict__ xxT_h,
    const float* __restrict__ S, const float* __restrict__ T,
    float* __restrict__ out)
{
    __shared__ __align__(16) _Float16 As[128 * 64];   // 16 KB (wp, rows o)
    __shared__ __align__(16) _Float16 Bh[64 * 64];    // 8 KB (xx hi, rows n)
    const int t = threadIdx.x, lane = t & 63, w = t >> 6;
    const int wr = w >> 1, wc = w & 1, l16 = lane & 15, lq = lane >> 4;
    const int o0 = blockIdx.x * 128, n0 = blockIdx.y * 64, b = blockIdx.z;

    f32x4 acc[2][4] = {};   // [i: n-subtile][j: o-subtile]

    for (int kb = 0; kb < 1024; kb += 64) {
        __syncthreads();
        #pragma unroll
        for (int p = 0; p < 4; p++) {
            int g = t + p * 256, row = g >> 3, s = g & 7;
            int col = ((s ^ (row & 7)) * 8);
            __builtin_amdgcn_global_load_lds(
                (gas_p)(const void*)(wp_h + (size_t)(o0 + row) * 1024 + kb + col),
                (las_p)(void*)&As[(p * 256 + w * 64) * 8], 16, 0, 0);
        }
        #pragma unroll
        for (int p = 0; p < 2; p++) {
            int g = t + p * 256, row = g >> 3, s = g & 7;
            int col = ((s ^ (row & 7)) * 8);
            size_t src = ((size_t)(b * 1024) + n0 + row) * 1024 + kb + col;
            __builtin_amdgcn_global_load_lds(
                (gas_p)(const void*)(xxT_h + src),
                (las_p)(void*)&Bh[(p * 256 + w * 64) * 8], 16, 0, 0);
        }
        __syncthreads();

        #pragma unroll
        for (int kk = 0; kk < 2; kk++) {
            const int sl = ((kk * 4 + lq) ^ (l16 & 7)) * 8;
            f16x8 axh[2], bw[4];
            #pragma unroll
            for (int i = 0; i < 2; i++)
                axh[i] = *(const f16x8*)(&Bh[(wc * 32 + i * 16 + l16) * 64 + sl]);
            #pragma unroll
            for (int j = 0; j < 4; j++)
                bw[j] = *(const f16x8*)(&As[(wr * 64 + j * 16 + l16) * 64 + sl]);
            #pragma unroll
            for (int i = 0; i < 2; i++)
                #pragma unroll
                for (int j = 0; j < 4; j++)
                    acc[i][j] = __builtin_amdgcn_mfma_f32_16x16x32_f16(axh[i], bw[j], acc[i][j], 0, 0, 0);
        }
    }

    // D[n][o]: n = n0+wc*32+i*16+lq*4+r (consecutive), o = o0+wr*64+j*16+l16.
    #pragma unroll
    for (int i = 0; i < 2; i++) {
        int nb = n0 + wc * 32 + i * 16 + lq * 4;
        #pragma unroll
        for (int j = 0; j < 4; j++) {
            int o = o0 + wr * 64 + j * 16 + l16;
            float sc = S[o], sh = T[o];
            float4 vv;
            vv.x = acc[i][j][0] * sc + sh;
            vv.y = acc[i][j][1] * sc + sh;
            vv.z = acc[i][j][2] * sc + sh;
            vv.w = acc[i][j][3] * sc + sh;
            *(float4*)(out + ((size_t)(b * 384) + o) * 1024 + nb) = vv;
        }
    }
}

// ---------------------------------------------------------------- launch

extern "C" void kernel_launch(void* const* d_in, const int* in_sizes, int n_in,
                              void* d_out, int out_size, void* d_ws, size_t ws_size,
                              hipStream_t stream) {
    const float* x   = (const float*)d_in[0];
    const float* wq  = (const float*)d_in[1];
    const float* bnq = (const float*)d_in[2];
    const float* wk  = (const float*)d_in[3];
    const float* bnk = (const float*)d_in[4];
    const float* wv  = (const float*)d_in[5];
    const float* bnv = (const float*)d_in[6];
    const float* wp  = (const float*)d_in[7];
    const float* bnp = (const float*)d_in[8];
    float* out = (float*)d_out;
    (void)in_sizes; (void)n_in; (void)out_size; (void)ws_size;

    char* ws = (char*)d_ws;
    size_t off = 0;
    auto alloc = [&](size_t bytes) {
        void* p = ws + off;
        off = (off + bytes + 255) & ~(size_t)255;
        return p;
    };
    // --- region A: dead after gemm_qkv; reused as xxT_h (needs >= 33.56 MB) ---
    _Float16* xT_hi = (_Float16*)alloc((size_t)16 * 1024 * 384 * 2);   // 12.58 MB
    _Float16* xT_lo = (_Float16*)alloc((size_t)16 * 1024 * 384 * 2);   // 12.58 MB
    _Float16* wqk_h = (_Float16*)alloc((size_t)512 * 384 * 2);
    _Float16* wv_h  = (_Float16*)alloc((size_t)1024 * 384 * 2);
    alloc((size_t)8 * 1024 * 1024);                                     // pad region A to > 33.56 MB
    _Float16* xxT_h = (_Float16*)d_ws;                                  // alias over region A
    // --- live buffers ---
    _Float16* wp_h  = (_Float16*)alloc((size_t)384 * 1024 * 2);
    float*    s_qkv = (float*)alloc(1536 * 4);
    float*    t_qkv = (float*)alloc(1536 * 4);
    float*    s_p   = (float*)alloc(384 * 4);
    float*    t_p   = (float*)alloc(384 * 4);
    _Float16* qT_h  = (_Float16*)alloc((size_t)16 * 8 * 1024 * 32 * 2); // 8.39 MB
    _Float16* kT_h  = (_Float16*)alloc((size_t)16 * 8 * 1024 * 32 * 2); // 8.39 MB
    _Float16* kT_l  = (_Float16*)alloc((size_t)16 * 8 * 1024 * 32 * 2); // 8.39 MB
    _Float16* vbuf  = (_Float16*)alloc((size_t)16 * 1024 * 1024 * 2);   // 33.55 MB

    prep<<<dim3(6, 16, 17), dim3(256), 0, stream>>>(
        x, wq, wk, wv, wp, bnq, bnk, bnv, bnp,
        xT_hi, xT_lo, wqk_h, wv_h, wp_h, s_qkv, t_qkv, s_p, t_p);

    gemm_qkv<<<dim3(12, 8, 16), dim3(256), 0, stream>>>(
        wqk_h, wv_h, xT_hi, xT_lo, s_qkv, t_qkv,
        qT_h, kT_h, kT_l, vbuf);

    attn<<<dim3(128, 8), dim3(256), 0, stream>>>(qT_h, kT_h, kT_l, vbuf, xxT_h);

    gemm_out<<<dim3(3, 16, 16), dim3(256), 0, stream>>>(wp_h, xxT_h, s_p, t_p, out);
}